// Round 11
// baseline (268.408 us; speedup 1.0000x reference)
//
#include <hip/hip_runtime.h>

#define NB 1024
#define NT 256
#define IND 10
#define HID 64

#define KSTEPS 14              // K = 448 (14 x 32)
#define XS 456                 // X row stride in halves (456/8=57 odd -> conflict-free b128)
#define WMF_HALVES (KSTEPS * 4 * 64 * 8)   // 28672 halves = 57344 B

typedef short bf16x8 __attribute__((ext_vector_type(8)));
typedef float f32x4 __attribute__((ext_vector_type(4)));

__device__ __forceinline__ int qmap(int kk) {
    if (kk < 10) return 1 + kk;
    if (kk < 20) return 11 * (kk - 10 + 1);
    int i = (kk - 20) / 10, c = (kk - 20) % 10;
    return 11 * (i + 1) + 1 + c;
}

__device__ __forceinline__ unsigned bf16rne(float x) {
    unsigned u = __float_as_uint(x);
    return (u + 0x7fffu + ((u >> 16) & 1u)) >> 16;
}
__device__ __forceinline__ unsigned pk2(float a, float b) {
    return bf16rne(a) | (bf16rne(b) << 16);
}

// X column semantics (K=448):
//  [0,128):   P (wave slice w at 32w+i, i<30; scaled by inv_k for comps<20)
//  [128,256): rel0 * P
//  [256,384): rel1 * P
//  [384,400): rel2 * Pd (Pd = P[0..9], P[10], P[20..24])
//  [400,410): rel ; [410,420): F ; [420,424): ttv, ttv*rel0, ttv*rel1, ttv*rel2
//  [424]: gate ; [425]: 1.0 (bias) ; rest 0
__device__ float wm_value(int kk, int j, const float* __restrict__ W1,
                          const float* __restrict__ b1) {
    if (kk < 384) {
        int sec = kk >> 7;
        int rem = kk & 127;
        int w = rem >> 5, i = rem & 31;
        if (i >= 30) return 0.f;
        int q = qmap(30 * w + i);
        if (sec == 0) return W1[(11 + q) * 64 + j] + W1[(132 + q) * 64 + j];
        if (sec == 1) return W1[(253 + q) * 64 + j];
        return W1[(374 + q) * 64 + j];
    }
    if (kk < 400) {
        int i = kk - 384;
        if (i < 10) return W1[(496 + i) * 64 + j];
        if (i == 10) return W1[506 * 64 + j];
        return W1[(507 + (i - 11)) * 64 + j];
    }
    if (kk < 410) return W1[(1 + (kk - 400)) * 64 + j];
    if (kk < 420) return W1[(512 + (kk - 410)) * 64 + j];
    if (kk == 420) return W1[11 * 64 + j] + W1[132 * 64 + j];
    if (kk == 421) return W1[253 * 64 + j];
    if (kk == 422) return W1[374 * 64 + j];
    if (kk == 423) return W1[495 * 64 + j];
    if (kk == 424) return W1[0 * 64 + j];
    if (kk == 425) return b1[j];
    return 0.f;
}

// Wmf in exact B-fragment order: record (s, jb) is 64 lanes x 8 halves:
// lane (n = lane&15, quad = lane>>4) holds Wm[32s + quad*8 + idx][16jb + n].
__global__ void pack_mfma_kernel(const float* __restrict__ W1,
                                 const float* __restrict__ b1,
                                 unsigned short* __restrict__ Wmf) {
    int idx = blockIdx.x * 256 + threadIdx.x;
    if (idx >= WMF_HALVES) return;
    int half = idx & 7;
    int lane = (idx >> 3) & 63;
    int rec = idx >> 9;           // s*4 + jb
    int s = rec >> 2, jb = rec & 3;
    int kk = 32 * s + (lane >> 4) * 8 + half;
    int j = 16 * jb + (lane & 15);
    Wmf[idx] = (unsigned short)bf16rne(wm_value(kk, j, W1, b1));
}

// ---------------------------------------------------------------------------
// presig v14 (unchanged -- round-9 winner, ~98 us): two-pass scan diet +
// #pragma unroll 2 on the MFMA K-loop keeps arch-VGPR <= 128 spill-free ->
// 2 blocks/CU co-residency (unified VGPR+AGPR budget 256/wave).
// ---------------------------------------------------------------------------
__global__ __launch_bounds__(256, 2) void presig14_kernel(
    const float* __restrict__ features, const unsigned short* __restrict__ Wmf,
    float* __restrict__ pre1) {
    const int b = blockIdx.x;
    const int tid = threadIdx.x;
    const int l = tid & 63;
    const int wu = tid >> 6;

    __shared__ __align__(16) unsigned short sX[64 * XS];    // 58368 B
    __shared__ __align__(16) float sFt[65 * IND];           // 2600 B
    __shared__ float sF0[IND];                              // 40 B
    __shared__ float sBase[128];                            // 512 B

    const float* fb = features + b * (NT * IND);
    if (tid < IND) sF0[tid] = fb[tid];
    if (tid < 128) sBase[tid] = 0.f;

    for (int tile = 0; tile < 4; ++tile) {
        const int t0 = tile * 64;

        // ---- stage this tile's feature rows t0..t0+64 (coalesced) ----
        {
            const int base = t0 * IND;
            for (int idx = tid; idx < 65 * IND; idx += 256)
                sFt[idx] = fb[min(base + idx, NT * IND - 1)];
        }
        __syncthreads();   // Bs: sFt (+ sF0/sBase on tile 0) ready

        const int r = t0 + l;
        float rf = (float)r;
        float rel[IND], inc[IND];
        {
            bool last = (r >= NT - 1);
#pragma unroll
            for (int c = 0; c < IND; ++c) {
                float frc = sFt[l * IND + c];
                rel[c] = frc - sF0[c];
                inc[c] = last ? 0.f : (sFt[(l + 1) * IND + c] - frc);
            }
        }
        float inv_r = (r > 0) ? 1.f / rf : 0.f;
        const int i0 = 3 * wu - 2;
        float g0 = rel[0], g1 = rel[1], g2 = rel[2];
        float s8 = 0.f, s9 = 0.f, s10 = 0.f;   // pass-A stash for xe[1]

        // ================= pass A: components 0..15 =================
        {
            float p[16];
            if (wu == 0) {
#pragma unroll
                for (int c = 0; c < 10; ++c) p[c] = rf * inc[c];
#pragma unroll
                for (int i = 0; i < 6; ++i) p[10 + i] = rel[i];
            } else {
#pragma unroll
                for (int q = 0; q < 16; ++q) {
                    int i = i0 + q / 10, c = q % 10;
                    p[q] = rel[i] * inc[c];
                }
            }
#pragma unroll
            for (int dsh = 0; dsh < 6; ++dsh) {
                const int d = 1 << dsh;
                bool ok = (l >= d);
#pragma unroll
                for (int i = 0; i < 16; ++i) {
                    float t = __shfl_up(p[i], d, 64);
                    if (ok) p[i] += t;
                }
            }
            float v[16];
#pragma unroll
            for (int i = 0; i < 16; ++i) {
                float e = __shfl_up(p[i], 1, 64);   // exclusive = inclusive[l-1]
                float x = sBase[wu * 32 + i] + ((l >= 1) ? e : 0.f);
                if (wu == 0) x *= inv_r;            // comps 0..15 all < 20
                v[i] = x;
            }
            if (l == 63) {
#pragma unroll
                for (int i = 0; i < 16; ++i) sBase[wu * 32 + i] += p[i];
            }
            // X groups q=0 (v0..7), q=1 (v8..15)
            uint4* xr = (uint4*)&sX[l * XS];
            uint4* x0 = (uint4*)&sX[l * XS + 128];
            uint4* x1 = (uint4*)&sX[l * XS + 256];
#pragma unroll
            for (int q = 0; q < 2; ++q) {
                uint4 tr, t0v, t1v;
                tr.x = pk2(v[8*q+0], v[8*q+1]); tr.y = pk2(v[8*q+2], v[8*q+3]);
                tr.z = pk2(v[8*q+4], v[8*q+5]); tr.w = pk2(v[8*q+6], v[8*q+7]);
                t0v.x = pk2(g0*v[8*q+0], g0*v[8*q+1]); t0v.y = pk2(g0*v[8*q+2], g0*v[8*q+3]);
                t0v.z = pk2(g0*v[8*q+4], g0*v[8*q+5]); t0v.w = pk2(g0*v[8*q+6], g0*v[8*q+7]);
                t1v.x = pk2(g1*v[8*q+0], g1*v[8*q+1]); t1v.y = pk2(g1*v[8*q+2], g1*v[8*q+3]);
                t1v.z = pk2(g1*v[8*q+4], g1*v[8*q+5]); t1v.w = pk2(g1*v[8*q+6], g1*v[8*q+7]);
                xr[wu * 4 + q] = tr; x0[wu * 4 + q] = t0v; x1[wu * 4 + q] = t1v;
            }
            if (wu == 0) {   // xe[0] + stash (needs v8..v10)
                uint4* xe = (uint4*)&sX[l * XS + 384];
                uint4 u;
                u.x = pk2(g2*v[0], g2*v[1]); u.y = pk2(g2*v[2], g2*v[3]);
                u.z = pk2(g2*v[4], g2*v[5]); u.w = pk2(g2*v[6], g2*v[7]);
                xe[0] = u;
                s8 = g2 * v[8]; s9 = g2 * v[9]; s10 = g2 * v[10];
            }
        }

        // ================= pass B: components 16..29 =================
        {
            float p[14];
            if (wu == 0) {
#pragma unroll
                for (int k = 0; k < 4; ++k) p[k] = rel[6 + k];        // comps 16..19
#pragma unroll
                for (int c = 0; c < 10; ++c) p[4 + c] = rel[0] * inc[c]; // 20..29
            } else {
#pragma unroll
                for (int k = 0; k < 14; ++k) {
                    int q = 16 + k;
                    int i = i0 + q / 10, c = q % 10;
                    p[k] = rel[i] * inc[c];
                }
            }
#pragma unroll
            for (int dsh = 0; dsh < 6; ++dsh) {
                const int d = 1 << dsh;
                bool ok = (l >= d);
#pragma unroll
                for (int k = 0; k < 14; ++k) {
                    float t = __shfl_up(p[k], d, 64);
                    if (ok) p[k] += t;
                }
            }
            float v[14];
#pragma unroll
            for (int k = 0; k < 14; ++k) {
                float e = __shfl_up(p[k], 1, 64);
                float x = sBase[wu * 32 + 16 + k] + ((l >= 1) ? e : 0.f);
                if (wu == 0 && k < 4) x *= inv_r;   // comps 16..19 only
                v[k] = x;
            }
            if (l == 63) {
#pragma unroll
                for (int k = 0; k < 14; ++k) sBase[wu * 32 + 16 + k] += p[k];
            }
            // X group q=2 (v16..23 = v[0..7]) + tail (v24..29 = v[8..13])
            uint4* xr = (uint4*)&sX[l * XS];
            uint4* x0 = (uint4*)&sX[l * XS + 128];
            uint4* x1 = (uint4*)&sX[l * XS + 256];
            {
                uint4 tr, t0v, t1v;
                tr.x = pk2(v[0], v[1]); tr.y = pk2(v[2], v[3]);
                tr.z = pk2(v[4], v[5]); tr.w = pk2(v[6], v[7]);
                t0v.x = pk2(g0*v[0], g0*v[1]); t0v.y = pk2(g0*v[2], g0*v[3]);
                t0v.z = pk2(g0*v[4], g0*v[5]); t0v.w = pk2(g0*v[6], g0*v[7]);
                t1v.x = pk2(g1*v[0], g1*v[1]); t1v.y = pk2(g1*v[2], g1*v[3]);
                t1v.z = pk2(g1*v[4], g1*v[5]); t1v.w = pk2(g1*v[6], g1*v[7]);
                xr[wu * 4 + 2] = tr; x0[wu * 4 + 2] = t0v; x1[wu * 4 + 2] = t1v;
            }
            {   // tail: v[24..29] + 2 zero halves
                uint4 tr, t0v, t1v;
                tr.x = pk2(v[8], v[9]);   tr.y = pk2(v[10], v[11]);
                tr.z = pk2(v[12], v[13]); tr.w = 0u;
                t0v.x = pk2(g0*v[8], g0*v[9]);   t0v.y = pk2(g0*v[10], g0*v[11]);
                t0v.z = pk2(g0*v[12], g0*v[13]); t0v.w = 0u;
                t1v.x = pk2(g1*v[8], g1*v[9]);   t1v.y = pk2(g1*v[10], g1*v[11]);
                t1v.z = pk2(g1*v[12], g1*v[13]); t1v.w = 0u;
                xr[wu * 4 + 3] = tr; x0[wu * 4 + 3] = t0v; x1[wu * 4 + 3] = t1v;
            }
            if (wu == 0) {   // extras xe[1..7]; comps 20..24 are v[4..8] here
                float ttv = 0.5f * (rf - 1.f) * inv_r;
                float gate = (r > 0) ? 1.f : 0.f;
                float fr0 = rel[0] + sF0[0], fr1 = rel[1] + sF0[1];
                float fr2 = rel[2] + sF0[2], fr3 = rel[3] + sF0[3];
                float fr4 = rel[4] + sF0[4], fr5 = rel[5] + sF0[5];
                float fr6 = rel[6] + sF0[6], fr7 = rel[7] + sF0[7];
                float fr8 = rel[8] + sF0[8], fr9 = rel[9] + sF0[9];
                uint4* xe = (uint4*)&sX[l * XS + 384];
                uint4 u;
                u.x = pk2(s8, s9);             u.y = pk2(s10, g2 * v[4]);
                u.z = pk2(g2*v[5], g2*v[6]);   u.w = pk2(g2*v[7], g2*v[8]);
                xe[1] = u;
                u.x = pk2(rel[0], rel[1]); u.y = pk2(rel[2], rel[3]);
                u.z = pk2(rel[4], rel[5]); u.w = pk2(rel[6], rel[7]);
                xe[2] = u;
                u.x = pk2(rel[8], rel[9]); u.y = pk2(fr0, fr1);
                u.z = pk2(fr2, fr3);       u.w = pk2(fr4, fr5);
                xe[3] = u;
                u.x = pk2(fr6, fr7); u.y = pk2(fr8, fr9);
                u.z = pk2(ttv, ttv * rel[0]); u.w = pk2(ttv * rel[1], ttv * rel[2]);
                xe[4] = u;
                u.x = pk2(gate, 1.0f); u.y = 0u; u.z = 0u; u.w = 0u;
                xe[5] = u;
                u.x = 0u; u.y = 0u; u.z = 0u; u.w = 0u;
                xe[6] = u; xe[7] = u;
            }
        }
        __syncthreads();   // Bx: X complete (cross-wave reads next)

        // ---- MFMA j-phase: unroll 2 bounds in-flight B-frags (~8 loads) ----
        {
            const int m = l & 15, quad = l >> 4;
            const unsigned short* arow = &sX[(16 * wu + m) * XS + 8 * quad];
            const bf16x8* bp = (const bf16x8*)Wmf;
            f32x4 ac0 = {0.f, 0.f, 0.f, 0.f}, ac1 = ac0, ac2 = ac0, ac3 = ac0;
#pragma unroll 2
            for (int s = 0; s < KSTEPS; ++s) {
                bf16x8 af = *(const bf16x8*)(arow + 32 * s);
                bf16x8 bf0 = bp[(s * 4 + 0) * 64 + l];
                bf16x8 bf1 = bp[(s * 4 + 1) * 64 + l];
                bf16x8 bf2 = bp[(s * 4 + 2) * 64 + l];
                bf16x8 bf3 = bp[(s * 4 + 3) * 64 + l];
                ac0 = __builtin_amdgcn_mfma_f32_16x16x32_bf16(af, bf0, ac0, 0, 0, 0);
                ac1 = __builtin_amdgcn_mfma_f32_16x16x32_bf16(af, bf1, ac1, 0, 0, 0);
                ac2 = __builtin_amdgcn_mfma_f32_16x16x32_bf16(af, bf2, ac2, 0, 0, 0);
                ac3 = __builtin_amdgcn_mfma_f32_16x16x32_bf16(af, bf3, ac3, 0, 0, 0);
            }
            float* op = pre1 + b * (NT * HID) + (t0 + 16 * wu) * HID + m;
            const int rowb = quad * 4;
#pragma unroll
            for (int reg = 0; reg < 4; ++reg) {
                op[(rowb + reg) * HID + 0]  = ac0[reg];
                op[(rowb + reg) * HID + 16] = ac1[reg];
                op[(rowb + reg) * HID + 32] = ac2[reg];
                op[(rowb + reg) * HID + 48] = ac3[reg];
            }
        }
        __syncthreads();   // Be: all X reads done before next tile rewrites
    }
}

// ---------------------------------------------------------------------------
// scan v7 (scan8_kernel): DUAL-BATCH MFMA scan.  Round-10 analysis: all
// 1024 chains already run concurrently (1 wave/SIMD), so scan dispatch time
// = per-chain serial time (925 cy/step vs ~190 cy issue -> ~75% un-hidden
// chain latency: 2 chained MFMAs + AGPR->VALU hazard + 6-deep DPP +
// readlane).  TLP cannot shorten a serial chain; the only lever is ILP:
// TWO independent batches per wave (512 blocks).  This is scan2's idea,
// which failed on register mechanics (64 per-lane W2 scalars un-holdable);
// the MFMA formulation changes the economics: W2 = 32 SHARED B-frag VGPRs
// (proven resident in scan6, VGPR=92), temps short-lived, 512-reg headroom
// at (64,1).  Batch B's h/cvt/MFMA issue fills batch A's MFMA/DPP stalls.
// Discriminators: WRITE ~1 KB & dur ~55-70 us = win; WRITE >> 1 MB = spill
// (revert scan6); dur ~98 clean = per-SIMD structural floor (scan done).
// ---------------------------------------------------------------------------
template <int CTRL, int RMASK>
__device__ __forceinline__ float dpp_add(float x) {
    int v = __builtin_amdgcn_update_dpp(0, __float_as_int(x), CTRL, RMASK, 0xf, false);
    return x + __int_as_float(v);
}

__device__ __forceinline__ float rl(float x, int lane) {
    return __uint_as_float(__builtin_amdgcn_readlane(__float_as_uint(x), lane));
}

__global__ __launch_bounds__(64, 1) void scan8_kernel(
    const float* __restrict__ pre1, const float* __restrict__ W1,
    const float* __restrict__ W2, const float* __restrict__ b2,
    const float* __restrict__ W3, const float* __restrict__ b3,
    float* __restrict__ out) {
    const int bA = blockIdx.x * 2, bB = bA + 1;
    const int l = threadIdx.x;
    const int m = l & 15, q = l >> 4;

    // ---- W2 B-fragments (8 x bf16x8 = 32 VGPRs), built once, SHARED ----
#define BUILD_B(dst, ks, nb) { \
        const int k0 = 32 * (ks) + 8 * q; \
        const int n = 16 * (nb) + m; \
        float x0 = W2[(k0 + 0) * 64 + n], x1 = W2[(k0 + 1) * 64 + n]; \
        float x2 = W2[(k0 + 2) * 64 + n], x3 = W2[(k0 + 3) * 64 + n]; \
        float x4 = W2[(k0 + 4) * 64 + n], x5 = W2[(k0 + 5) * 64 + n]; \
        float x6 = W2[(k0 + 6) * 64 + n], x7 = W2[(k0 + 7) * 64 + n]; \
        unsigned u0, u1, u2, u3; \
        asm("v_cvt_pk_bf16_f32 %0, %1, %2" : "=v"(u0) : "v"(x0), "v"(x1)); \
        asm("v_cvt_pk_bf16_f32 %0, %1, %2" : "=v"(u1) : "v"(x2), "v"(x3)); \
        asm("v_cvt_pk_bf16_f32 %0, %1, %2" : "=v"(u2) : "v"(x4), "v"(x5)); \
        asm("v_cvt_pk_bf16_f32 %0, %1, %2" : "=v"(u3) : "v"(x6), "v"(x7)); \
        union { unsigned uu[4]; bf16x8 v; } cv; \
        cv.uu[0] = u0; cv.uu[1] = u1; cv.uu[2] = u2; cv.uu[3] = u3; \
        dst = cv.v; }

    bf16x8 Bf0, Bf1, Bf2, Bf3, Bf4, Bf5, Bf6, Bf7;
    BUILD_B(Bf0, 0, 0) BUILD_B(Bf1, 0, 1) BUILD_B(Bf2, 0, 2) BUILD_B(Bf3, 0, 3)
    BUILD_B(Bf4, 1, 0) BUILD_B(Bf5, 1, 1) BUILD_B(Bf6, 1, 2) BUILD_B(Bf7, 1, 3)
#undef BUILD_B

    // ---- per-lane invariants (shared between batches) ----
    float w1a[8], w1b[8];
#pragma unroll
    for (int i = 0; i < 8; ++i) {
        w1a[i] = W1[522 * 64 + 8 * q + i];
        w1b[i] = W1[522 * 64 + 32 + 8 * q + i];
    }
    float b2s0 = b2[m],      b2s1 = b2[16 + m],
          b2s2 = b2[32 + m], b2s3 = b2[48 + m];
    float w3s0 = W3[m] * 0.25f,      w3s1 = W3[16 + m] * 0.25f,
          w3s2 = W3[32 + m] * 0.25f, w3s3 = W3[48 + m] * 0.25f;
    float b3v = b3[0];

    const float* pA_ = pre1 + bA * (NT * HID);
    const float* pB_ = pre1 + bB * (NT * HID);
    const int o1 = 8 * q, o2 = 8 * q + 4, o3 = 32 + 8 * q, o4 = 36 + 8 * q;
    float deltaA = 0.f, deltaB = 0.f;
    float outbufA = 0.f, outbufB = 0.f;

#define STEPD(pa0, pa1, pa2, pa3, pb0, pb1, pb2, pb3, mm) { \
        float fA0 = fmaxf(fmaf(deltaA, w1a[0], (pa0).x), 0.f); \
        float fA1 = fmaxf(fmaf(deltaA, w1a[1], (pa0).y), 0.f); \
        float fA2 = fmaxf(fmaf(deltaA, w1a[2], (pa0).z), 0.f); \
        float fA3 = fmaxf(fmaf(deltaA, w1a[3], (pa0).w), 0.f); \
        float fA4 = fmaxf(fmaf(deltaA, w1a[4], (pa1).x), 0.f); \
        float fA5 = fmaxf(fmaf(deltaA, w1a[5], (pa1).y), 0.f); \
        float fA6 = fmaxf(fmaf(deltaA, w1a[6], (pa1).z), 0.f); \
        float fA7 = fmaxf(fmaf(deltaA, w1a[7], (pa1).w), 0.f); \
        float gA0 = fmaxf(fmaf(deltaA, w1b[0], (pa2).x), 0.f); \
        float gA1 = fmaxf(fmaf(deltaA, w1b[1], (pa2).y), 0.f); \
        float gA2 = fmaxf(fmaf(deltaA, w1b[2], (pa2).z), 0.f); \
        float gA3 = fmaxf(fmaf(deltaA, w1b[3], (pa2).w), 0.f); \
        float gA4 = fmaxf(fmaf(deltaA, w1b[4], (pa3).x), 0.f); \
        float gA5 = fmaxf(fmaf(deltaA, w1b[5], (pa3).y), 0.f); \
        float gA6 = fmaxf(fmaf(deltaA, w1b[6], (pa3).z), 0.f); \
        float gA7 = fmaxf(fmaf(deltaA, w1b[7], (pa3).w), 0.f); \
        float fB0 = fmaxf(fmaf(deltaB, w1a[0], (pb0).x), 0.f); \
        float fB1 = fmaxf(fmaf(deltaB, w1a[1], (pb0).y), 0.f); \
        float fB2 = fmaxf(fmaf(deltaB, w1a[2], (pb0).z), 0.f); \
        float fB3 = fmaxf(fmaf(deltaB, w1a[3], (pb0).w), 0.f); \
        float fB4 = fmaxf(fmaf(deltaB, w1a[4], (pb1).x), 0.f); \
        float fB5 = fmaxf(fmaf(deltaB, w1a[5], (pb1).y), 0.f); \
        float fB6 = fmaxf(fmaf(deltaB, w1a[6], (pb1).z), 0.f); \
        float fB7 = fmaxf(fmaf(deltaB, w1a[7], (pb1).w), 0.f); \
        float gB0 = fmaxf(fmaf(deltaB, w1b[0], (pb2).x), 0.f); \
        float gB1 = fmaxf(fmaf(deltaB, w1b[1], (pb2).y), 0.f); \
        float gB2 = fmaxf(fmaf(deltaB, w1b[2], (pb2).z), 0.f); \
        float gB3 = fmaxf(fmaf(deltaB, w1b[3], (pb2).w), 0.f); \
        float gB4 = fmaxf(fmaf(deltaB, w1b[4], (pb3).x), 0.f); \
        float gB5 = fmaxf(fmaf(deltaB, w1b[5], (pb3).y), 0.f); \
        float gB6 = fmaxf(fmaf(deltaB, w1b[6], (pb3).z), 0.f); \
        float gB7 = fmaxf(fmaf(deltaB, w1b[7], (pb3).w), 0.f); \
        unsigned uA0, uA1, uA2, uA3, vA0, vA1, vA2, vA3; \
        unsigned uB0, uB1, uB2, uB3, vB0, vB1, vB2, vB3; \
        asm("v_cvt_pk_bf16_f32 %0, %1, %2" : "=v"(uA0) : "v"(fA0), "v"(fA1)); \
        asm("v_cvt_pk_bf16_f32 %0, %1, %2" : "=v"(uA1) : "v"(fA2), "v"(fA3)); \
        asm("v_cvt_pk_bf16_f32 %0, %1, %2" : "=v"(uA2) : "v"(fA4), "v"(fA5)); \
        asm("v_cvt_pk_bf16_f32 %0, %1, %2" : "=v"(uA3) : "v"(fA6), "v"(fA7)); \
        asm("v_cvt_pk_bf16_f32 %0, %1, %2" : "=v"(vA0) : "v"(gA0), "v"(gA1)); \
        asm("v_cvt_pk_bf16_f32 %0, %1, %2" : "=v"(vA1) : "v"(gA2), "v"(gA3)); \
        asm("v_cvt_pk_bf16_f32 %0, %1, %2" : "=v"(vA2) : "v"(gA4), "v"(gA5)); \
        asm("v_cvt_pk_bf16_f32 %0, %1, %2" : "=v"(vA3) : "v"(gA6), "v"(gA7)); \
        asm("v_cvt_pk_bf16_f32 %0, %1, %2" : "=v"(uB0) : "v"(fB0), "v"(fB1)); \
        asm("v_cvt_pk_bf16_f32 %0, %1, %2" : "=v"(uB1) : "v"(fB2), "v"(fB3)); \
        asm("v_cvt_pk_bf16_f32 %0, %1, %2" : "=v"(uB2) : "v"(fB4), "v"(fB5)); \
        asm("v_cvt_pk_bf16_f32 %0, %1, %2" : "=v"(uB3) : "v"(fB6), "v"(fB7)); \
        asm("v_cvt_pk_bf16_f32 %0, %1, %2" : "=v"(vB0) : "v"(gB0), "v"(gB1)); \
        asm("v_cvt_pk_bf16_f32 %0, %1, %2" : "=v"(vB1) : "v"(gB2), "v"(gB3)); \
        asm("v_cvt_pk_bf16_f32 %0, %1, %2" : "=v"(vB2) : "v"(gB4), "v"(gB5)); \
        asm("v_cvt_pk_bf16_f32 %0, %1, %2" : "=v"(vB3) : "v"(gB6), "v"(gB7)); \
        union { unsigned uu[4]; bf16x8 v; } cAa, cAb, cBa, cBb; \
        cAa.uu[0] = uA0; cAa.uu[1] = uA1; cAa.uu[2] = uA2; cAa.uu[3] = uA3; \
        cAb.uu[0] = vA0; cAb.uu[1] = vA1; cAb.uu[2] = vA2; cAb.uu[3] = vA3; \
        cBa.uu[0] = uB0; cBa.uu[1] = uB1; cBa.uu[2] = uB2; cBa.uu[3] = uB3; \
        cBb.uu[0] = vB0; cBb.uu[1] = vB1; cBb.uu[2] = vB2; cBb.uu[3] = vB3; \
        f32x4 z = {0.f, 0.f, 0.f, 0.f}; \
        f32x4 cA0 = __builtin_amdgcn_mfma_f32_16x16x32_bf16(cAa.v, Bf0, z, 0, 0, 0); \
        f32x4 cB0 = __builtin_amdgcn_mfma_f32_16x16x32_bf16(cBa.v, Bf0, z, 0, 0, 0); \
        f32x4 cA1 = __builtin_amdgcn_mfma_f32_16x16x32_bf16(cAa.v, Bf1, z, 0, 0, 0); \
        f32x4 cB1 = __builtin_amdgcn_mfma_f32_16x16x32_bf16(cBa.v, Bf1, z, 0, 0, 0); \
        f32x4 cA2 = __builtin_amdgcn_mfma_f32_16x16x32_bf16(cAa.v, Bf2, z, 0, 0, 0); \
        f32x4 cB2 = __builtin_amdgcn_mfma_f32_16x16x32_bf16(cBa.v, Bf2, z, 0, 0, 0); \
        f32x4 cA3 = __builtin_amdgcn_mfma_f32_16x16x32_bf16(cAa.v, Bf3, z, 0, 0, 0); \
        f32x4 cB3 = __builtin_amdgcn_mfma_f32_16x16x32_bf16(cBa.v, Bf3, z, 0, 0, 0); \
        cA0 = __builtin_amdgcn_mfma_f32_16x16x32_bf16(cAb.v, Bf4, cA0, 0, 0, 0); \
        cB0 = __builtin_amdgcn_mfma_f32_16x16x32_bf16(cBb.v, Bf4, cB0, 0, 0, 0); \
        cA1 = __builtin_amdgcn_mfma_f32_16x16x32_bf16(cAb.v, Bf5, cA1, 0, 0, 0); \
        cB1 = __builtin_amdgcn_mfma_f32_16x16x32_bf16(cBb.v, Bf5, cB1, 0, 0, 0); \
        cA2 = __builtin_amdgcn_mfma_f32_16x16x32_bf16(cAb.v, Bf6, cA2, 0, 0, 0); \
        cB2 = __builtin_amdgcn_mfma_f32_16x16x32_bf16(cBb.v, Bf6, cB2, 0, 0, 0); \
        cA3 = __builtin_amdgcn_mfma_f32_16x16x32_bf16(cAb.v, Bf7, cA3, 0, 0, 0); \
        cB3 = __builtin_amdgcn_mfma_f32_16x16x32_bf16(cBb.v, Bf7, cB3, 0, 0, 0); \
        float qvA, qvB; \
        qvA =      fmaxf(cA0[0] + b2s0, 0.f) * w3s0; \
        qvB =      fmaxf(cB0[0] + b2s0, 0.f) * w3s0; \
        qvA = fmaf(fmaxf(cA1[0] + b2s1, 0.f), w3s1, qvA); \
        qvB = fmaf(fmaxf(cB1[0] + b2s1, 0.f), w3s1, qvB); \
        qvA = fmaf(fmaxf(cA2[0] + b2s2, 0.f), w3s2, qvA); \
        qvB = fmaf(fmaxf(cB2[0] + b2s2, 0.f), w3s2, qvB); \
        qvA = fmaf(fmaxf(cA3[0] + b2s3, 0.f), w3s3, qvA); \
        qvB = fmaf(fmaxf(cB3[0] + b2s3, 0.f), w3s3, qvB); \
        qvA = dpp_add<0x111, 0xf>(qvA); qvB = dpp_add<0x111, 0xf>(qvB); \
        qvA = dpp_add<0x112, 0xf>(qvA); qvB = dpp_add<0x112, 0xf>(qvB); \
        qvA = dpp_add<0x114, 0xf>(qvA); qvB = dpp_add<0x114, 0xf>(qvB); \
        qvA = dpp_add<0x118, 0xf>(qvA); qvB = dpp_add<0x118, 0xf>(qvB); \
        qvA = dpp_add<0x142, 0xa>(qvA); qvB = dpp_add<0x142, 0xa>(qvB); \
        qvA = dpp_add<0x143, 0xc>(qvA); qvB = dpp_add<0x143, 0xc>(qvB); \
        deltaA = rl(qvA, 63) + b3v; \
        deltaB = rl(qvB, 63) + b3v; \
        if (l == ((mm) & 63)) { outbufA = deltaA; outbufB = deltaB; } \
        if (((mm) & 63) == 63) { \
            out[bA * NT + ((mm) & ~63) + l] = outbufA; \
            out[bB * NT + ((mm) & ~63) + l] = outbufB; } }

    // ---- dual ping-pong 4-step prefetch ring ----
    float4 sA0a, sA0b, sA0c, sA0d, sA1a, sA1b, sA1c, sA1d,
           sA2a, sA2b, sA2c, sA2d, sA3a, sA3b, sA3c, sA3d;
    float4 sB0a, sB0b, sB0c, sB0d, sB1a, sB1b, sB1c, sB1d,
           sB2a, sB2b, sB2c, sB2d, sB3a, sB3b, sB3c, sB3d;
    float4 tA0a, tA0b, tA0c, tA0d, tA1a, tA1b, tA1c, tA1d,
           tA2a, tA2b, tA2c, tA2d, tA3a, tA3b, tA3c, tA3d;
    float4 tB0a, tB0b, tB0c, tB0d, tB1a, tB1b, tB1c, tB1d,
           tB2a, tB2b, tB2c, tB2d, tB3a, tB3b, tB3c, tB3d;
#define LDD(daa, dab, dac, dad, dba, dbb, dbc, dbd, tt) { \
        const float* baseA = &pA_[(tt) * 64]; \
        daa = *(const float4*)&baseA[o1]; dab = *(const float4*)&baseA[o2]; \
        dac = *(const float4*)&baseA[o3]; dad = *(const float4*)&baseA[o4]; \
        const float* baseB = &pB_[(tt) * 64]; \
        dba = *(const float4*)&baseB[o1]; dbb = *(const float4*)&baseB[o2]; \
        dbc = *(const float4*)&baseB[o3]; dbd = *(const float4*)&baseB[o4]; }

    LDD(sA0a, sA0b, sA0c, sA0d, sB0a, sB0b, sB0c, sB0d, 0)
    LDD(sA1a, sA1b, sA1c, sA1d, sB1a, sB1b, sB1c, sB1d, 1)
    LDD(sA2a, sA2b, sA2c, sA2d, sB2a, sB2b, sB2c, sB2d, 2)
    LDD(sA3a, sA3b, sA3c, sA3d, sB3a, sB3b, sB3c, sB3d, 3)
    LDD(tA0a, tA0b, tA0c, tA0d, tB0a, tB0b, tB0c, tB0d, 4)
    LDD(tA1a, tA1b, tA1c, tA1d, tB1a, tB1b, tB1c, tB1d, 5)
    LDD(tA2a, tA2b, tA2c, tA2d, tB2a, tB2b, tB2c, tB2d, 6)
    LDD(tA3a, tA3b, tA3c, tA3d, tB3a, tB3b, tB3c, tB3d, 7)

    for (int g = 0; g < NT; g += 8) {
        STEPD(sA0a, sA0b, sA0c, sA0d, sB0a, sB0b, sB0c, sB0d, g + 0)
        STEPD(sA1a, sA1b, sA1c, sA1d, sB1a, sB1b, sB1c, sB1d, g + 1)
        STEPD(sA2a, sA2b, sA2c, sA2d, sB2a, sB2b, sB2c, sB2d, g + 2)
        STEPD(sA3a, sA3b, sA3c, sA3d, sB3a, sB3b, sB3c, sB3d, g + 3)
        LDD(sA0a, sA0b, sA0c, sA0d, sB0a, sB0b, sB0c, sB0d, min(g + 8,  NT - 1))
        LDD(sA1a, sA1b, sA1c, sA1d, sB1a, sB1b, sB1c, sB1d, min(g + 9,  NT - 1))
        LDD(sA2a, sA2b, sA2c, sA2d, sB2a, sB2b, sB2c, sB2d, min(g + 10, NT - 1))
        LDD(sA3a, sA3b, sA3c, sA3d, sB3a, sB3b, sB3c, sB3d, min(g + 11, NT - 1))
        STEPD(tA0a, tA0b, tA0c, tA0d, tB0a, tB0b, tB0c, tB0d, g + 4)
        STEPD(tA1a, tA1b, tA1c, tA1d, tB1a, tB1b, tB1c, tB1d, g + 5)
        STEPD(tA2a, tA2b, tA2c, tA2d, tB2a, tB2b, tB2c, tB2d, g + 6)
        STEPD(tA3a, tA3b, tA3c, tA3d, tB3a, tB3b, tB3c, tB3d, g + 7)
        LDD(tA0a, tA0b, tA0c, tA0d, tB0a, tB0b, tB0c, tB0d, min(g + 12, NT - 1))
        LDD(tA1a, tA1b, tA1c, tA1d, tB1a, tB1b, tB1c, tB1d, min(g + 13, NT - 1))
        LDD(tA2a, tA2b, tA2c, tA2d, tB2a, tB2b, tB2c, tB2d, min(g + 14, NT - 1))
        LDD(tA3a, tA3b, tA3c, tA3d, tB3a, tB3b, tB3c, tB3d, min(g + 15, NT - 1))
    }
#undef LDD
#undef STEPD
}

// ---------------------------------------------------------------------------
// Fallback (round-1 fused kernel) if workspace is too small.
// ---------------------------------------------------------------------------
__global__ __launch_bounds__(256) void logsig_hedge_fallback(
    const float* __restrict__ features, const float* __restrict__ W1,
    const float* __restrict__ b1, const float* __restrict__ W2,
    const float* __restrict__ b2, const float* __restrict__ W3,
    const float* __restrict__ b3, float* __restrict__ out) {
    const int b = blockIdx.x;
    const int tid = threadIdx.x;
    const int j = tid & 63;
    const int s = tid >> 6;

    __shared__ __align__(16) float sF[NT * IND];
    __shared__ __align__(16) float sSig[128];
    __shared__ float sA[IND], sB[IND], sC[IND * IND];
    __shared__ float sRel[IND];
    __shared__ __align__(16) float sPart[4 * 64];
    __shared__ __align__(16) float sH1[64];

    for (int idx = tid; idx < NT * IND; idx += 256)
        sF[idx] = features[b * (NT * IND) + idx];
    if (tid < 100) sC[tid] = 0.f;
    else if (tid < 110) sA[tid - 100] = 0.f;
    else if (tid < 120) sB[tid - 110] = 0.f;
    else if (tid >= 121 && tid < 128) sSig[tid] = 0.f;

    float vs[32], vb[32], vc[32];
#pragma unroll
    for (int mm = 0; mm < 32; ++mm) {
        int mp = 32 * s + mm;
        if (mp < 121) {
            vs[mm] = W1[(11 + mp) * 64 + j] + W1[(132 + mp) * 64 + j];
            vb[mm] = W1[(253 + mp) * 64 + j];
            vc[mm] = W1[(374 + mp) * 64 + j];
        } else { vs[mm] = 0.f; vb[mm] = 0.f; vc[mm] = 0.f; }
    }
    float ex[17];
#pragma unroll
    for (int q = 0; q < 17; ++q) ex[q] = 0.f;
    if (s == 1) {
#pragma unroll
        for (int q = 0; q < 11; ++q) ex[q] = W1[q * 64 + j];
    } else if (s == 2) {
#pragma unroll
        for (int q = 0; q < 10; ++q) ex[q] = W1[(512 + q) * 64 + j];
        ex[10] = b1[j];
    } else if (s == 3) {
#pragma unroll
        for (int q = 0; q < 17; ++q) ex[q] = W1[(495 + q) * 64 + j];
    }
    float w2p[16];
#pragma unroll
    for (int ii = 0; ii < 16; ++ii) w2p[ii] = W2[(16 * s + ii) * 64 + j];

    float w1l = 0.f, b2j = 0.f, w3j = 0.f, b3v = 0.f;
    if (s == 0) { w1l = W1[522 * 64 + j]; b2j = b2[j]; w3j = W3[j]; b3v = b3[0]; }
    float delta = 0.f;

    __syncthreads();

    for (int m = 0; m < NT; ++m) {
        if (m > 0) {
            if (tid < 100) {
                int i = tid / 10, c = tid % 10;
                float rp = sF[(m - 1) * 10 + i] - sF[i];
                float ic = sF[m * 10 + c] - sF[(m - 1) * 10 + c];
                sC[tid] += rp * ic;
            } else if (tid < 110) {
                int i = tid - 100;
                sA[i] += (float)(m - 1) * (sF[m * 10 + i] - sF[(m - 1) * 10 + i]);
            } else if (tid < 120) {
                int i = tid - 110;
                sB[i] += sF[(m - 1) * 10 + i] - sF[i];
            }
            __syncthreads();
            float inv_k = 1.0f / (float)m;
            if (tid == 0) sSig[0] = 0.5f * (float)(m - 1) * inv_k;
            else if (tid < 11) sSig[tid] = inv_k * sA[tid - 1];
            else if (tid < 121) {
                int i = tid / 11 - 1, c = tid % 11;
                sSig[tid] = (c == 0) ? inv_k * sB[i] : sC[i * 10 + (c - 1)];
            } else if (tid < 131) {
                int f = tid - 121;
                sRel[f] = sF[m * 10 + f] - sF[f];
            }
            __syncthreads();
        }
        float part = 0.f;
        if (m > 0) {
            float pa = 0.f, pb = 0.f, pc = 0.f;
#pragma unroll
            for (int q = 0; q < 8; ++q) {
                float4 sv = *(const float4*)&sSig[32 * s + 4 * q];
                pa = fmaf(sv.x, vs[4 * q + 0], pa);
                pb = fmaf(sv.x, vb[4 * q + 0], pb);
                pc = fmaf(sv.x, vc[4 * q + 0], pc);
                pa = fmaf(sv.y, vs[4 * q + 1], pa);
                pb = fmaf(sv.y, vb[4 * q + 1], pb);
                pc = fmaf(sv.y, vc[4 * q + 1], pc);
                pa = fmaf(sv.z, vs[4 * q + 2], pa);
                pb = fmaf(sv.z, vb[4 * q + 2], pb);
                pc = fmaf(sv.z, vc[4 * q + 2], pc);
                pa = fmaf(sv.w, vs[4 * q + 3], pa);
                pb = fmaf(sv.w, vb[4 * q + 3], pb);
                pc = fmaf(sv.w, vc[4 * q + 3], pc);
            }
            part = pa + sRel[0] * pb + sRel[1] * pc;
            if (s == 3) {
                float pd = 0.f;
#pragma unroll
                for (int q = 0; q < 17; ++q) pd = fmaf(sSig[q], ex[q], pd);
                part = fmaf(sRel[2], pd, part);
            }
            if (s == 1) {
                part += ex[0];
#pragma unroll
                for (int i = 0; i < 10; ++i) part = fmaf(sRel[i], ex[1 + i], part);
            }
        }
        if (s == 2) {
            float pf = ex[10];
#pragma unroll
            for (int f = 0; f < 10; ++f) pf = fmaf(sF[m * 10 + f], ex[f], pf);
            part += pf;
        }
        sPart[s * 64 + j] = part;
        __syncthreads();
        if (s == 0) {
            float x = sPart[j] + sPart[64 + j] + sPart[128 + j] + sPart[192 + j];
            sH1[j] = fmaxf(fmaf(delta, w1l, x), 0.f);
        }
        __syncthreads();
        {
            float hp = 0.f;
#pragma unroll
            for (int q = 0; q < 4; ++q) {
                float4 hv = *(const float4*)&sH1[16 * s + 4 * q];
                hp = fmaf(hv.x, w2p[4 * q + 0], hp);
                hp = fmaf(hv.y, w2p[4 * q + 1], hp);
                hp = fmaf(hv.z, w2p[4 * q + 2], hp);
                hp = fmaf(hv.w, w2p[4 * q + 3], hp);
            }
            sPart[s * 64 + j] = hp;
        }
        __syncthreads();
        if (s == 0) {
            float x2 = sPart[j] + sPart[64 + j] + sPart[128 + j] + sPart[192 + j] + b2j;
            float h2 = fmaxf(x2, 0.f);
            float dv = h2 * w3j;
#pragma unroll
            for (int off = 32; off > 0; off >>= 1) dv += __shfl_xor(dv, off, 64);
            delta = dv + b3v;
            if (j == 0) out[b * NT + m] = delta;
        }
        __syncthreads();
    }
}

extern "C" void kernel_launch(void* const* d_in, const int* in_sizes, int n_in,
                              void* d_out, int out_size, void* d_ws, size_t ws_size,
                              hipStream_t stream) {
    const float* features = (const float*)d_in[0];
    const float* W1 = (const float*)d_in[1];
    const float* b1 = (const float*)d_in[2];
    const float* W2 = (const float*)d_in[3];
    const float* b2 = (const float*)d_in[4];
    const float* W3 = (const float*)d_in[5];
    const float* b3 = (const float*)d_in[6];
    float* out = (float*)d_out;

    const size_t wmf_bytes = (size_t)WMF_HALVES * 2;                 // 57344
    const size_t w_pad     = ((wmf_bytes + 255) / 256) * 256;
    const size_t pre_bytes = (size_t)NB * NT * HID * sizeof(float);  // 64 MiB
    if (ws_size >= w_pad + pre_bytes) {
        unsigned short* Wmf = (unsigned short*)d_ws;
        float* pre1 = (float*)((char*)d_ws + w_pad);
        pack_mfma_kernel<<<(WMF_HALVES + 255) / 256, 256, 0, stream>>>(W1, b1, Wmf);
        presig14_kernel<<<NB, 256, 0, stream>>>(features, Wmf, pre1);
        scan8_kernel<<<NB / 2, 64, 0, stream>>>(pre1, W1, W2, b2, W3, b3, out);
    } else {
        logsig_hedge_fallback<<<NB, 256, 0, stream>>>(features, W1, b1, W2, b2, W3, b3, out);
    }
}

// Round 14
// 254.221 us; speedup vs baseline: 1.0558x; 1.0558x over previous
//
#include <hip/hip_runtime.h>

#define NB 1024
#define NT 256
#define IND 10
#define HID 64

#define KSTEPS 14              // K = 448 (14 x 32)
#define XS 456                 // X row stride in halves (456/8=57 odd -> conflict-free b128)
#define WMF_HALVES (KSTEPS * 4 * 64 * 8)   // 28672 halves = 57344 B

typedef short bf16x8 __attribute__((ext_vector_type(8)));
typedef float f32x4 __attribute__((ext_vector_type(4)));

__device__ __forceinline__ int qmap(int kk) {
    if (kk < 10) return 1 + kk;
    if (kk < 20) return 11 * (kk - 10 + 1);
    int i = (kk - 20) / 10, c = (kk - 20) % 10;
    return 11 * (i + 1) + 1 + c;
}

__device__ __forceinline__ unsigned bf16rne(float x) {
    unsigned u = __float_as_uint(x);
    return (u + 0x7fffu + ((u >> 16) & 1u)) >> 16;
}
__device__ __forceinline__ unsigned pk2(float a, float b) {
    return bf16rne(a) | (bf16rne(b) << 16);
}

// X column semantics (K=448):
//  [0,128):   P (wave slice w at 32w+i, i<30; scaled by inv_k for comps<20)
//  [128,256): rel0 * P
//  [256,384): rel1 * P
//  [384,400): rel2 * Pd (Pd = P[0..9], P[10], P[20..24])
//  [400,410): rel ; [410,420): F ; [420,424): ttv, ttv*rel0, ttv*rel1, ttv*rel2
//  [424]: gate ; [425]: 1.0 (bias) ; rest 0
__device__ float wm_value(int kk, int j, const float* __restrict__ W1,
                          const float* __restrict__ b1) {
    if (kk < 384) {
        int sec = kk >> 7;
        int rem = kk & 127;
        int w = rem >> 5, i = rem & 31;
        if (i >= 30) return 0.f;
        int q = qmap(30 * w + i);
        if (sec == 0) return W1[(11 + q) * 64 + j] + W1[(132 + q) * 64 + j];
        if (sec == 1) return W1[(253 + q) * 64 + j];
        return W1[(374 + q) * 64 + j];
    }
    if (kk < 400) {
        int i = kk - 384;
        if (i < 10) return W1[(496 + i) * 64 + j];
        if (i == 10) return W1[506 * 64 + j];
        return W1[(507 + (i - 11)) * 64 + j];
    }
    if (kk < 410) return W1[(1 + (kk - 400)) * 64 + j];
    if (kk < 420) return W1[(512 + (kk - 410)) * 64 + j];
    if (kk == 420) return W1[11 * 64 + j] + W1[132 * 64 + j];
    if (kk == 421) return W1[253 * 64 + j];
    if (kk == 422) return W1[374 * 64 + j];
    if (kk == 423) return W1[495 * 64 + j];
    if (kk == 424) return W1[0 * 64 + j];
    if (kk == 425) return b1[j];
    return 0.f;
}

// Wmf in exact B-fragment order: record (s, jb) is 64 lanes x 8 halves:
// lane (n = lane&15, quad = lane>>4) holds Wm[32s + quad*8 + idx][16jb + n].
__global__ void pack_mfma_kernel(const float* __restrict__ W1,
                                 const float* __restrict__ b1,
                                 unsigned short* __restrict__ Wmf) {
    int idx = blockIdx.x * 256 + threadIdx.x;
    if (idx >= WMF_HALVES) return;
    int half = idx & 7;
    int lane = (idx >> 3) & 63;
    int rec = idx >> 9;           // s*4 + jb
    int s = rec >> 2, jb = rec & 3;
    int kk = 32 * s + (lane >> 4) * 8 + half;
    int j = 16 * jb + (lane & 15);
    Wmf[idx] = (unsigned short)bf16rne(wm_value(kk, j, W1, b1));
}

// ---------------------------------------------------------------------------
// presig v14 (unchanged -- round-9 winner, ~98 us): two-pass scan diet +
// #pragma unroll 2 on the MFMA K-loop keeps arch-VGPR <= 128 spill-free ->
// 2 blocks/CU co-residency (unified VGPR+AGPR budget 256/wave).
// ---------------------------------------------------------------------------
__global__ __launch_bounds__(256, 2) void presig14_kernel(
    const float* __restrict__ features, const unsigned short* __restrict__ Wmf,
    float* __restrict__ pre1) {
    const int b = blockIdx.x;
    const int tid = threadIdx.x;
    const int l = tid & 63;
    const int wu = tid >> 6;

    __shared__ __align__(16) unsigned short sX[64 * XS];    // 58368 B
    __shared__ __align__(16) float sFt[65 * IND];           // 2600 B
    __shared__ float sF0[IND];                              // 40 B
    __shared__ float sBase[128];                            // 512 B

    const float* fb = features + b * (NT * IND);
    if (tid < IND) sF0[tid] = fb[tid];
    if (tid < 128) sBase[tid] = 0.f;

    for (int tile = 0; tile < 4; ++tile) {
        const int t0 = tile * 64;

        // ---- stage this tile's feature rows t0..t0+64 (coalesced) ----
        {
            const int base = t0 * IND;
            for (int idx = tid; idx < 65 * IND; idx += 256)
                sFt[idx] = fb[min(base + idx, NT * IND - 1)];
        }
        __syncthreads();   // Bs: sFt (+ sF0/sBase on tile 0) ready

        const int r = t0 + l;
        float rf = (float)r;
        float rel[IND], inc[IND];
        {
            bool last = (r >= NT - 1);
#pragma unroll
            for (int c = 0; c < IND; ++c) {
                float frc = sFt[l * IND + c];
                rel[c] = frc - sF0[c];
                inc[c] = last ? 0.f : (sFt[(l + 1) * IND + c] - frc);
            }
        }
        float inv_r = (r > 0) ? 1.f / rf : 0.f;
        const int i0 = 3 * wu - 2;
        float g0 = rel[0], g1 = rel[1], g2 = rel[2];
        float s8 = 0.f, s9 = 0.f, s10 = 0.f;   // pass-A stash for xe[1]

        // ================= pass A: components 0..15 =================
        {
            float p[16];
            if (wu == 0) {
#pragma unroll
                for (int c = 0; c < 10; ++c) p[c] = rf * inc[c];
#pragma unroll
                for (int i = 0; i < 6; ++i) p[10 + i] = rel[i];
            } else {
#pragma unroll
                for (int q = 0; q < 16; ++q) {
                    int i = i0 + q / 10, c = q % 10;
                    p[q] = rel[i] * inc[c];
                }
            }
#pragma unroll
            for (int dsh = 0; dsh < 6; ++dsh) {
                const int d = 1 << dsh;
                bool ok = (l >= d);
#pragma unroll
                for (int i = 0; i < 16; ++i) {
                    float t = __shfl_up(p[i], d, 64);
                    if (ok) p[i] += t;
                }
            }
            float v[16];
#pragma unroll
            for (int i = 0; i < 16; ++i) {
                float e = __shfl_up(p[i], 1, 64);   // exclusive = inclusive[l-1]
                float x = sBase[wu * 32 + i] + ((l >= 1) ? e : 0.f);
                if (wu == 0) x *= inv_r;            // comps 0..15 all < 20
                v[i] = x;
            }
            if (l == 63) {
#pragma unroll
                for (int i = 0; i < 16; ++i) sBase[wu * 32 + i] += p[i];
            }
            // X groups q=0 (v0..7), q=1 (v8..15)
            uint4* xr = (uint4*)&sX[l * XS];
            uint4* x0 = (uint4*)&sX[l * XS + 128];
            uint4* x1 = (uint4*)&sX[l * XS + 256];
#pragma unroll
            for (int q = 0; q < 2; ++q) {
                uint4 tr, t0v, t1v;
                tr.x = pk2(v[8*q+0], v[8*q+1]); tr.y = pk2(v[8*q+2], v[8*q+3]);
                tr.z = pk2(v[8*q+4], v[8*q+5]); tr.w = pk2(v[8*q+6], v[8*q+7]);
                t0v.x = pk2(g0*v[8*q+0], g0*v[8*q+1]); t0v.y = pk2(g0*v[8*q+2], g0*v[8*q+3]);
                t0v.z = pk2(g0*v[8*q+4], g0*v[8*q+5]); t0v.w = pk2(g0*v[8*q+6], g0*v[8*q+7]);
                t1v.x = pk2(g1*v[8*q+0], g1*v[8*q+1]); t1v.y = pk2(g1*v[8*q+2], g1*v[8*q+3]);
                t1v.z = pk2(g1*v[8*q+4], g1*v[8*q+5]); t1v.w = pk2(g1*v[8*q+6], g1*v[8*q+7]);
                xr[wu * 4 + q] = tr; x0[wu * 4 + q] = t0v; x1[wu * 4 + q] = t1v;
            }
            if (wu == 0) {   // xe[0] + stash (needs v8..v10)
                uint4* xe = (uint4*)&sX[l * XS + 384];
                uint4 u;
                u.x = pk2(g2*v[0], g2*v[1]); u.y = pk2(g2*v[2], g2*v[3]);
                u.z = pk2(g2*v[4], g2*v[5]); u.w = pk2(g2*v[6], g2*v[7]);
                xe[0] = u;
                s8 = g2 * v[8]; s9 = g2 * v[9]; s10 = g2 * v[10];
            }
        }

        // ================= pass B: components 16..29 =================
        {
            float p[14];
            if (wu == 0) {
#pragma unroll
                for (int k = 0; k < 4; ++k) p[k] = rel[6 + k];        // comps 16..19
#pragma unroll
                for (int c = 0; c < 10; ++c) p[4 + c] = rel[0] * inc[c]; // 20..29
            } else {
#pragma unroll
                for (int k = 0; k < 14; ++k) {
                    int q = 16 + k;
                    int i = i0 + q / 10, c = q % 10;
                    p[k] = rel[i] * inc[c];
                }
            }
#pragma unroll
            for (int dsh = 0; dsh < 6; ++dsh) {
                const int d = 1 << dsh;
                bool ok = (l >= d);
#pragma unroll
                for (int k = 0; k < 14; ++k) {
                    float t = __shfl_up(p[k], d, 64);
                    if (ok) p[k] += t;
                }
            }
            float v[14];
#pragma unroll
            for (int k = 0; k < 14; ++k) {
                float e = __shfl_up(p[k], 1, 64);
                float x = sBase[wu * 32 + 16 + k] + ((l >= 1) ? e : 0.f);
                if (wu == 0 && k < 4) x *= inv_r;   // comps 16..19 only
                v[k] = x;
            }
            if (l == 63) {
#pragma unroll
                for (int k = 0; k < 14; ++k) sBase[wu * 32 + 16 + k] += p[k];
            }
            // X group q=2 (v16..23 = v[0..7]) + tail (v24..29 = v[8..13])
            uint4* xr = (uint4*)&sX[l * XS];
            uint4* x0 = (uint4*)&sX[l * XS + 128];
            uint4* x1 = (uint4*)&sX[l * XS + 256];
            {
                uint4 tr, t0v, t1v;
                tr.x = pk2(v[0], v[1]); tr.y = pk2(v[2], v[3]);
                tr.z = pk2(v[4], v[5]); tr.w = pk2(v[6], v[7]);
                t0v.x = pk2(g0*v[0], g0*v[1]); t0v.y = pk2(g0*v[2], g0*v[3]);
                t0v.z = pk2(g0*v[4], g0*v[5]); t0v.w = pk2(g0*v[6], g0*v[7]);
                t1v.x = pk2(g1*v[0], g1*v[1]); t1v.y = pk2(g1*v[2], g1*v[3]);
                t1v.z = pk2(g1*v[4], g1*v[5]); t1v.w = pk2(g1*v[6], g1*v[7]);
                xr[wu * 4 + 2] = tr; x0[wu * 4 + 2] = t0v; x1[wu * 4 + 2] = t1v;
            }
            {   // tail: v[24..29] + 2 zero halves
                uint4 tr, t0v, t1v;
                tr.x = pk2(v[8], v[9]);   tr.y = pk2(v[10], v[11]);
                tr.z = pk2(v[12], v[13]); tr.w = 0u;
                t0v.x = pk2(g0*v[8], g0*v[9]);   t0v.y = pk2(g0*v[10], g0*v[11]);
                t0v.z = pk2(g0*v[12], g0*v[13]); t0v.w = 0u;
                t1v.x = pk2(g1*v[8], g1*v[9]);   t1v.y = pk2(g1*v[10], g1*v[11]);
                t1v.z = pk2(g1*v[12], g1*v[13]); t1v.w = 0u;
                xr[wu * 4 + 3] = tr; x0[wu * 4 + 3] = t0v; x1[wu * 4 + 3] = t1v;
            }
            if (wu == 0) {   // extras xe[1..7]; comps 20..24 are v[4..8] here
                float ttv = 0.5f * (rf - 1.f) * inv_r;
                float gate = (r > 0) ? 1.f : 0.f;
                float fr0 = rel[0] + sF0[0], fr1 = rel[1] + sF0[1];
                float fr2 = rel[2] + sF0[2], fr3 = rel[3] + sF0[3];
                float fr4 = rel[4] + sF0[4], fr5 = rel[5] + sF0[5];
                float fr6 = rel[6] + sF0[6], fr7 = rel[7] + sF0[7];
                float fr8 = rel[8] + sF0[8], fr9 = rel[9] + sF0[9];
                uint4* xe = (uint4*)&sX[l * XS + 384];
                uint4 u;
                u.x = pk2(s8, s9);             u.y = pk2(s10, g2 * v[4]);
                u.z = pk2(g2*v[5], g2*v[6]);   u.w = pk2(g2*v[7], g2*v[8]);
                xe[1] = u;
                u.x = pk2(rel[0], rel[1]); u.y = pk2(rel[2], rel[3]);
                u.z = pk2(rel[4], rel[5]); u.w = pk2(rel[6], rel[7]);
                xe[2] = u;
                u.x = pk2(rel[8], rel[9]); u.y = pk2(fr0, fr1);
                u.z = pk2(fr2, fr3);       u.w = pk2(fr4, fr5);
                xe[3] = u;
                u.x = pk2(fr6, fr7); u.y = pk2(fr8, fr9);
                u.z = pk2(ttv, ttv * rel[0]); u.w = pk2(ttv * rel[1], ttv * rel[2]);
                xe[4] = u;
                u.x = pk2(gate, 1.0f); u.y = 0u; u.z = 0u; u.w = 0u;
                xe[5] = u;
                u.x = 0u; u.y = 0u; u.z = 0u; u.w = 0u;
                xe[6] = u; xe[7] = u;
            }
        }
        __syncthreads();   // Bx: X complete (cross-wave reads next)

        // ---- MFMA j-phase: unroll 2 bounds in-flight B-frags (~8 loads) ----
        {
            const int m = l & 15, quad = l >> 4;
            const unsigned short* arow = &sX[(16 * wu + m) * XS + 8 * quad];
            const bf16x8* bp = (const bf16x8*)Wmf;
            f32x4 ac0 = {0.f, 0.f, 0.f, 0.f}, ac1 = ac0, ac2 = ac0, ac3 = ac0;
#pragma unroll 2
            for (int s = 0; s < KSTEPS; ++s) {
                bf16x8 af = *(const bf16x8*)(arow + 32 * s);
                bf16x8 bf0 = bp[(s * 4 + 0) * 64 + l];
                bf16x8 bf1 = bp[(s * 4 + 1) * 64 + l];
                bf16x8 bf2 = bp[(s * 4 + 2) * 64 + l];
                bf16x8 bf3 = bp[(s * 4 + 3) * 64 + l];
                ac0 = __builtin_amdgcn_mfma_f32_16x16x32_bf16(af, bf0, ac0, 0, 0, 0);
                ac1 = __builtin_amdgcn_mfma_f32_16x16x32_bf16(af, bf1, ac1, 0, 0, 0);
                ac2 = __builtin_amdgcn_mfma_f32_16x16x32_bf16(af, bf2, ac2, 0, 0, 0);
                ac3 = __builtin_amdgcn_mfma_f32_16x16x32_bf16(af, bf3, ac3, 0, 0, 0);
            }
            float* op = pre1 + b * (NT * HID) + (t0 + 16 * wu) * HID + m;
            const int rowb = quad * 4;
#pragma unroll
            for (int reg = 0; reg < 4; ++reg) {
                op[(rowb + reg) * HID + 0]  = ac0[reg];
                op[(rowb + reg) * HID + 16] = ac1[reg];
                op[(rowb + reg) * HID + 32] = ac2[reg];
                op[(rowb + reg) * HID + 48] = ac3[reg];
            }
        }
        __syncthreads();   // Be: all X reads done before next tile rewrites
    }
}

// ---------------------------------------------------------------------------
// scan v9 (scan9b_kernel): round-11 chain-shortened scan with the reduce-lane
// BUG FIXED (round-13 resubmit: round-12's bench never ran -- container
// infra failure, not a kernel failure).  Round-11 failed (absmax 185)
// because row_shr moves values toward HIGHER lanes: after the 4 row_shr
// stages the 16-lane row sum sits in lane 15 (scan6's original sequence
// continued with row_bcast15/31 accumulating into lane 63 -- consistent).
// readlane(qv, 0) read a partial.  Fix: readlane(qv, 15).  Coverage
// argument (verified): quad-0 lanes m=0..15 compute columns {m, m+16,
// m+32, m+48} exactly once, so the sum of lanes 0..15 equals the full
// 64-column dot product; no 0.25 prescale.  Chain edits under test:
// (1) independent MFMA pair (c,d from zero-acc, summed on VALU) removes
// one MFMA latency; (2) 4-stage reduce instead of 6.
// Discriminator: dur ~85-92 = chain win; dur ~98 = hazard floor (scan done).
// ---------------------------------------------------------------------------
template <int CTRL, int RMASK>
__device__ __forceinline__ float dpp_add(float x) {
    int v = __builtin_amdgcn_update_dpp(0, __float_as_int(x), CTRL, RMASK, 0xf, false);
    return x + __int_as_float(v);
}

__device__ __forceinline__ float rl(float x, int lane) {
    return __uint_as_float(__builtin_amdgcn_readlane(__float_as_uint(x), lane));
}

__global__ __launch_bounds__(64, 1) void scan9b_kernel(
    const float* __restrict__ pre1, const float* __restrict__ W1,
    const float* __restrict__ W2, const float* __restrict__ b2,
    const float* __restrict__ W3, const float* __restrict__ b3,
    float* __restrict__ out) {
    const int b = blockIdx.x;
    const int l = threadIdx.x;
    const int m = l & 15, q = l >> 4;

    // ---- W2 B-fragments (8 x bf16x8 = 32 VGPRs), built once ----
#define BUILD_B(dst, ks, nb) { \
        const int k0 = 32 * (ks) + 8 * q; \
        const int n = 16 * (nb) + m; \
        float x0 = W2[(k0 + 0) * 64 + n], x1 = W2[(k0 + 1) * 64 + n]; \
        float x2 = W2[(k0 + 2) * 64 + n], x3 = W2[(k0 + 3) * 64 + n]; \
        float x4 = W2[(k0 + 4) * 64 + n], x5 = W2[(k0 + 5) * 64 + n]; \
        float x6 = W2[(k0 + 6) * 64 + n], x7 = W2[(k0 + 7) * 64 + n]; \
        unsigned u0, u1, u2, u3; \
        asm("v_cvt_pk_bf16_f32 %0, %1, %2" : "=v"(u0) : "v"(x0), "v"(x1)); \
        asm("v_cvt_pk_bf16_f32 %0, %1, %2" : "=v"(u1) : "v"(x2), "v"(x3)); \
        asm("v_cvt_pk_bf16_f32 %0, %1, %2" : "=v"(u2) : "v"(x4), "v"(x5)); \
        asm("v_cvt_pk_bf16_f32 %0, %1, %2" : "=v"(u3) : "v"(x6), "v"(x7)); \
        union { unsigned uu[4]; bf16x8 v; } cv; \
        cv.uu[0] = u0; cv.uu[1] = u1; cv.uu[2] = u2; cv.uu[3] = u3; \
        dst = cv.v; }

    bf16x8 Bf0, Bf1, Bf2, Bf3, Bf4, Bf5, Bf6, Bf7;
    BUILD_B(Bf0, 0, 0) BUILD_B(Bf1, 0, 1) BUILD_B(Bf2, 0, 2) BUILD_B(Bf3, 0, 3)
    BUILD_B(Bf4, 1, 0) BUILD_B(Bf5, 1, 1) BUILD_B(Bf6, 1, 2) BUILD_B(Bf7, 1, 3)
#undef BUILD_B

    // ---- per-lane invariants ----
    float w1a[8], w1b[8];
#pragma unroll
    for (int i = 0; i < 8; ++i) {
        w1a[i] = W1[522 * 64 + 8 * q + i];
        w1b[i] = W1[522 * 64 + 32 + 8 * q + i];
    }
    float b2s0 = b2[m],      b2s1 = b2[16 + m],
          b2s2 = b2[32 + m], b2s3 = b2[48 + m];
    float w3s0 = W3[m],      w3s1 = W3[16 + m],
          w3s2 = W3[32 + m], w3s3 = W3[48 + m];   // raw (16-lane reduce, no /4)
    float b3v = b3[0];

    const float* pb_ = pre1 + b * (NT * HID);
    const int o1 = 8 * q, o2 = 8 * q + 4, o3 = 32 + 8 * q, o4 = 36 + 8 * q;
    float delta = 0.f;
    float outbuf = 0.f;

#define STEP9(pa, pb, pc, pd, mm) { \
        float hA0 = fmaxf(fmaf(delta, w1a[0], (pa).x), 0.f); \
        float hA1 = fmaxf(fmaf(delta, w1a[1], (pa).y), 0.f); \
        float hA2 = fmaxf(fmaf(delta, w1a[2], (pa).z), 0.f); \
        float hA3 = fmaxf(fmaf(delta, w1a[3], (pa).w), 0.f); \
        float hA4 = fmaxf(fmaf(delta, w1a[4], (pb).x), 0.f); \
        float hA5 = fmaxf(fmaf(delta, w1a[5], (pb).y), 0.f); \
        float hA6 = fmaxf(fmaf(delta, w1a[6], (pb).z), 0.f); \
        float hA7 = fmaxf(fmaf(delta, w1a[7], (pb).w), 0.f); \
        float hB0 = fmaxf(fmaf(delta, w1b[0], (pc).x), 0.f); \
        float hB1 = fmaxf(fmaf(delta, w1b[1], (pc).y), 0.f); \
        float hB2 = fmaxf(fmaf(delta, w1b[2], (pc).z), 0.f); \
        float hB3 = fmaxf(fmaf(delta, w1b[3], (pc).w), 0.f); \
        float hB4 = fmaxf(fmaf(delta, w1b[4], (pd).x), 0.f); \
        float hB5 = fmaxf(fmaf(delta, w1b[5], (pd).y), 0.f); \
        float hB6 = fmaxf(fmaf(delta, w1b[6], (pd).z), 0.f); \
        float hB7 = fmaxf(fmaf(delta, w1b[7], (pd).w), 0.f); \
        unsigned uA0, uA1, uA2, uA3, uB0, uB1, uB2, uB3; \
        asm("v_cvt_pk_bf16_f32 %0, %1, %2" : "=v"(uA0) : "v"(hA0), "v"(hA1)); \
        asm("v_cvt_pk_bf16_f32 %0, %1, %2" : "=v"(uA1) : "v"(hA2), "v"(hA3)); \
        asm("v_cvt_pk_bf16_f32 %0, %1, %2" : "=v"(uA2) : "v"(hA4), "v"(hA5)); \
        asm("v_cvt_pk_bf16_f32 %0, %1, %2" : "=v"(uA3) : "v"(hA6), "v"(hA7)); \
        asm("v_cvt_pk_bf16_f32 %0, %1, %2" : "=v"(uB0) : "v"(hB0), "v"(hB1)); \
        asm("v_cvt_pk_bf16_f32 %0, %1, %2" : "=v"(uB1) : "v"(hB2), "v"(hB3)); \
        asm("v_cvt_pk_bf16_f32 %0, %1, %2" : "=v"(uB2) : "v"(hB4), "v"(hB5)); \
        asm("v_cvt_pk_bf16_f32 %0, %1, %2" : "=v"(uB3) : "v"(hB6), "v"(hB7)); \
        union { unsigned uu[4]; bf16x8 v; } cA, cB; \
        cA.uu[0] = uA0; cA.uu[1] = uA1; cA.uu[2] = uA2; cA.uu[3] = uA3; \
        cB.uu[0] = uB0; cB.uu[1] = uB1; cB.uu[2] = uB2; cB.uu[3] = uB3; \
        f32x4 z = {0.f, 0.f, 0.f, 0.f}; \
        f32x4 c0 = __builtin_amdgcn_mfma_f32_16x16x32_bf16(cA.v, Bf0, z, 0, 0, 0); \
        f32x4 d0 = __builtin_amdgcn_mfma_f32_16x16x32_bf16(cB.v, Bf4, z, 0, 0, 0); \
        f32x4 c1 = __builtin_amdgcn_mfma_f32_16x16x32_bf16(cA.v, Bf1, z, 0, 0, 0); \
        f32x4 d1 = __builtin_amdgcn_mfma_f32_16x16x32_bf16(cB.v, Bf5, z, 0, 0, 0); \
        f32x4 c2 = __builtin_amdgcn_mfma_f32_16x16x32_bf16(cA.v, Bf2, z, 0, 0, 0); \
        f32x4 d2 = __builtin_amdgcn_mfma_f32_16x16x32_bf16(cB.v, Bf6, z, 0, 0, 0); \
        f32x4 c3 = __builtin_amdgcn_mfma_f32_16x16x32_bf16(cA.v, Bf3, z, 0, 0, 0); \
        f32x4 d3 = __builtin_amdgcn_mfma_f32_16x16x32_bf16(cB.v, Bf7, z, 0, 0, 0); \
        float v0 = c0[0] + d0[0]; \
        float v1 = c1[0] + d1[0]; \
        float v2 = c2[0] + d2[0]; \
        float v3 = c3[0] + d3[0]; \
        float e0 = fmaxf(v0 + b2s0, 0.f) * w3s0; \
        float e1 = fmaxf(v1 + b2s1, 0.f) * w3s1; \
        float e2 = fmaxf(v2 + b2s2, 0.f) * w3s2; \
        float e3 = fmaxf(v3 + b2s3, 0.f) * w3s3; \
        float qv = (e0 + e1) + (e2 + e3); \
        qv = dpp_add<0x111, 0xf>(qv); \
        qv = dpp_add<0x112, 0xf>(qv); \
        qv = dpp_add<0x114, 0xf>(qv); \
        qv = dpp_add<0x118, 0xf>(qv); \
        delta = rl(qv, 15) + b3v; \
        if (l == ((mm) & 63)) outbuf = delta; \
        if (((mm) & 63) == 63) out[b * NT + ((mm) & ~63) + l] = outbuf; }

    // ---- ping-pong 4-step prefetch ring (no register rotation) ----
    float4 s0a, s0b, s0c, s0d, s1a, s1b, s1c, s1d,
           s2a, s2b, s2c, s2d, s3a, s3b, s3c, s3d;
    float4 t0a, t0b, t0c, t0d, t1a, t1b, t1c, t1d,
           t2a, t2b, t2c, t2d, t3a, t3b, t3c, t3d;
#define LD(dsta, dstb, dstc, dstd, tt) { \
        const float* base = &pb_[(tt) * 64]; \
        dsta = *(const float4*)&base[o1]; dstb = *(const float4*)&base[o2]; \
        dstc = *(const float4*)&base[o3]; dstd = *(const float4*)&base[o4]; }

    LD(s0a, s0b, s0c, s0d, 0) LD(s1a, s1b, s1c, s1d, 1)
    LD(s2a, s2b, s2c, s2d, 2) LD(s3a, s3b, s3c, s3d, 3)
    LD(t0a, t0b, t0c, t0d, 4) LD(t1a, t1b, t1c, t1d, 5)
    LD(t2a, t2b, t2c, t2d, 6) LD(t3a, t3b, t3c, t3d, 7)

    for (int g = 0; g < NT; g += 8) {
        STEP9(s0a, s0b, s0c, s0d, g + 0)
        STEP9(s1a, s1b, s1c, s1d, g + 1)
        STEP9(s2a, s2b, s2c, s2d, g + 2)
        STEP9(s3a, s3b, s3c, s3d, g + 3)
        LD(s0a, s0b, s0c, s0d, min(g + 8,  NT - 1))
        LD(s1a, s1b, s1c, s1d, min(g + 9,  NT - 1))
        LD(s2a, s2b, s2c, s2d, min(g + 10, NT - 1))
        LD(s3a, s3b, s3c, s3d, min(g + 11, NT - 1))
        STEP9(t0a, t0b, t0c, t0d, g + 4)
        STEP9(t1a, t1b, t1c, t1d, g + 5)
        STEP9(t2a, t2b, t2c, t2d, g + 6)
        STEP9(t3a, t3b, t3c, t3d, g + 7)
        LD(t0a, t0b, t0c, t0d, min(g + 12, NT - 1))
        LD(t1a, t1b, t1c, t1d, min(g + 13, NT - 1))
        LD(t2a, t2b, t2c, t2d, min(g + 14, NT - 1))
        LD(t3a, t3b, t3c, t3d, min(g + 15, NT - 1))
    }
#undef LD
#undef STEP9
}

// ---------------------------------------------------------------------------
// Fallback (round-1 fused kernel) if workspace is too small.
// ---------------------------------------------------------------------------
__global__ __launch_bounds__(256) void logsig_hedge_fallback(
    const float* __restrict__ features, const float* __restrict__ W1,
    const float* __restrict__ b1, const float* __restrict__ W2,
    const float* __restrict__ b2, const float* __restrict__ W3,
    const float* __restrict__ b3, float* __restrict__ out) {
    const int b = blockIdx.x;
    const int tid = threadIdx.x;
    const int j = tid & 63;
    const int s = tid >> 6;

    __shared__ __align__(16) float sF[NT * IND];
    __shared__ __align__(16) float sSig[128];
    __shared__ float sA[IND], sB[IND], sC[IND * IND];
    __shared__ float sRel[IND];
    __shared__ __align__(16) float sPart[4 * 64];
    __shared__ __align__(16) float sH1[64];

    for (int idx = tid; idx < NT * IND; idx += 256)
        sF[idx] = features[b * (NT * IND) + idx];
    if (tid < 100) sC[tid] = 0.f;
    else if (tid < 110) sA[tid - 100] = 0.f;
    else if (tid < 120) sB[tid - 110] = 0.f;
    else if (tid >= 121 && tid < 128) sSig[tid] = 0.f;

    float vs[32], vb[32], vc[32];
#pragma unroll
    for (int mm = 0; mm < 32; ++mm) {
        int mp = 32 * s + mm;
        if (mp < 121) {
            vs[mm] = W1[(11 + mp) * 64 + j] + W1[(132 + mp) * 64 + j];
            vb[mm] = W1[(253 + mp) * 64 + j];
            vc[mm] = W1[(374 + mp) * 64 + j];
        } else { vs[mm] = 0.f; vb[mm] = 0.f; vc[mm] = 0.f; }
    }
    float ex[17];
#pragma unroll
    for (int q = 0; q < 17; ++q) ex[q] = 0.f;
    if (s == 1) {
#pragma unroll
        for (int q = 0; q < 11; ++q) ex[q] = W1[q * 64 + j];
    } else if (s == 2) {
#pragma unroll
        for (int q = 0; q < 10; ++q) ex[q] = W1[(512 + q) * 64 + j];
        ex[10] = b1[j];
    } else if (s == 3) {
#pragma unroll
        for (int q = 0; q < 17; ++q) ex[q] = W1[(495 + q) * 64 + j];
    }
    float w2p[16];
#pragma unroll
    for (int ii = 0; ii < 16; ++ii) w2p[ii] = W2[(16 * s + ii) * 64 + j];

    float w1l = 0.f, b2j = 0.f, w3j = 0.f, b3v = 0.f;
    if (s == 0) { w1l = W1[522 * 64 + j]; b2j = b2[j]; w3j = W3[j]; b3v = b3[0]; }
    float delta = 0.f;

    __syncthreads();

    for (int m = 0; m < NT; ++m) {
        if (m > 0) {
            if (tid < 100) {
                int i = tid / 10, c = tid % 10;
                float rp = sF[(m - 1) * 10 + i] - sF[i];
                float ic = sF[m * 10 + c] - sF[(m - 1) * 10 + c];
                sC[tid] += rp * ic;
            } else if (tid < 110) {
                int i = tid - 100;
                sA[i] += (float)(m - 1) * (sF[m * 10 + i] - sF[(m - 1) * 10 + i]);
            } else if (tid < 120) {
                int i = tid - 110;
                sB[i] += sF[(m - 1) * 10 + i] - sF[i];
            }
            __syncthreads();
            float inv_k = 1.0f / (float)m;
            if (tid == 0) sSig[0] = 0.5f * (float)(m - 1) * inv_k;
            else if (tid < 11) sSig[tid] = inv_k * sA[tid - 1];
            else if (tid < 121) {
                int i = tid / 11 - 1, c = tid % 11;
                sSig[tid] = (c == 0) ? inv_k * sB[i] : sC[i * 10 + (c - 1)];
            } else if (tid < 131) {
                int f = tid - 121;
                sRel[f] = sF[m * 10 + f] - sF[f];
            }
            __syncthreads();
        }
        float part = 0.f;
        if (m > 0) {
            float pa = 0.f, pb = 0.f, pc = 0.f;
#pragma unroll
            for (int q = 0; q < 8; ++q) {
                float4 sv = *(const float4*)&sSig[32 * s + 4 * q];
                pa = fmaf(sv.x, vs[4 * q + 0], pa);
                pb = fmaf(sv.x, vb[4 * q + 0], pb);
                pc = fmaf(sv.x, vc[4 * q + 0], pc);
                pa = fmaf(sv.y, vs[4 * q + 1], pa);
                pb = fmaf(sv.y, vb[4 * q + 1], pb);
                pc = fmaf(sv.y, vc[4 * q + 1], pc);
                pa = fmaf(sv.z, vs[4 * q + 2], pa);
                pb = fmaf(sv.z, vb[4 * q + 2], pb);
                pc = fmaf(sv.z, vc[4 * q + 2], pc);
                pa = fmaf(sv.w, vs[4 * q + 3], pa);
                pb = fmaf(sv.w, vb[4 * q + 3], pb);
                pc = fmaf(sv.w, vc[4 * q + 3], pc);
            }
            part = pa + sRel[0] * pb + sRel[1] * pc;
            if (s == 3) {
                float pd = 0.f;
#pragma unroll
                for (int q = 0; q < 17; ++q) pd = fmaf(sSig[q], ex[q], pd);
                part = fmaf(sRel[2], pd, part);
            }
            if (s == 1) {
                part += ex[0];
#pragma unroll
                for (int i = 0; i < 10; ++i) part = fmaf(sRel[i], ex[1 + i], part);
            }
        }
        if (s == 2) {
            float pf = ex[10];
#pragma unroll
            for (int f = 0; f < 10; ++f) pf = fmaf(sF[m * 10 + f], ex[f], pf);
            part += pf;
        }
        sPart[s * 64 + j] = part;
        __syncthreads();
        if (s == 0) {
            float x = sPart[j] + sPart[64 + j] + sPart[128 + j] + sPart[192 + j];
            sH1[j] = fmaxf(fmaf(delta, w1l, x), 0.f);
        }
        __syncthreads();
        {
            float hp = 0.f;
#pragma unroll
            for (int q = 0; q < 4; ++q) {
                float4 hv = *(const float4*)&sH1[16 * s + 4 * q];
                hp = fmaf(hv.x, w2p[4 * q + 0], hp);
                hp = fmaf(hv.y, w2p[4 * q + 1], hp);
                hp = fmaf(hv.z, w2p[4 * q + 2], hp);
                hp = fmaf(hv.w, w2p[4 * q + 3], hp);
            }
            sPart[s * 64 + j] = hp;
        }
        __syncthreads();
        if (s == 0) {
            float x2 = sPart[j] + sPart[64 + j] + sPart[128 + j] + sPart[192 + j] + b2j;
            float h2 = fmaxf(x2, 0.f);
            float dv = h2 * w3j;
#pragma unroll
            for (int off = 32; off > 0; off >>= 1) dv += __shfl_xor(dv, off, 64);
            delta = dv + b3v;
            if (j == 0) out[b * NT + m] = delta;
        }
        __syncthreads();
    }
}

extern "C" void kernel_launch(void* const* d_in, const int* in_sizes, int n_in,
                              void* d_out, int out_size, void* d_ws, size_t ws_size,
                              hipStream_t stream) {
    const float* features = (const float*)d_in[0];
    const float* W1 = (const float*)d_in[1];
    const float* b1 = (const float*)d_in[2];
    const float* W2 = (const float*)d_in[3];
    const float* b2 = (const float*)d_in[4];
    const float* W3 = (const float*)d_in[5];
    const float* b3 = (const float*)d_in[6];
    float* out = (float*)d_out;

    const size_t wmf_bytes = (size_t)WMF_HALVES * 2;                 // 57344
    const size_t w_pad     = ((wmf_bytes + 255) / 256) * 256;
    const size_t pre_bytes = (size_t)NB * NT * HID * sizeof(float);  // 64 MiB
    if (ws_size >= w_pad + pre_bytes) {
        unsigned short* Wmf = (unsigned short*)d_ws;
        float* pre1 = (float*)((char*)d_ws + w_pad);
        pack_mfma_kernel<<<(WMF_HALVES + 255) / 256, 256, 0, stream>>>(W1, b1, Wmf);
        presig14_kernel<<<NB, 256, 0, stream>>>(features, Wmf, pre1);
        scan9b_kernel<<<NB, 64, 0, stream>>>(pre1, W1, W2, b2, W3, b3, out);
    } else {
        logsig_hedge_fallback<<<NB, 256, 0, stream>>>(features, W1, b1, W2, b2, W3, b3, out);
    }
}

// Round 15
// 243.309 us; speedup vs baseline: 1.1032x; 1.0448x over previous
//
#include <hip/hip_runtime.h>

#define NB 1024
#define NT 256
#define IND 10
#define HID 64

#define KSTEPS 14              // K = 448 (14 x 32)
#define XS 456                 // X row stride in halves (456/8=57 odd -> conflict-free b128)
#define WMF_HALVES (KSTEPS * 4 * 64 * 8)   // 28672 halves = 57344 B

typedef short bf16x8 __attribute__((ext_vector_type(8)));
typedef float f32x4 __attribute__((ext_vector_type(4)));

__device__ __forceinline__ int qmap(int kk) {
    if (kk < 10) return 1 + kk;
    if (kk < 20) return 11 * (kk - 10 + 1);
    int i = (kk - 20) / 10, c = (kk - 20) % 10;
    return 11 * (i + 1) + 1 + c;
}

__device__ __forceinline__ unsigned bf16rne(float x) {
    unsigned u = __float_as_uint(x);
    return (u + 0x7fffu + ((u >> 16) & 1u)) >> 16;
}
__device__ __forceinline__ unsigned pk2(float a, float b) {
    return bf16rne(a) | (bf16rne(b) << 16);
}

// X column semantics (K=448):
//  [0,128):   P (wave slice w at 32w+i, i<30; scaled by inv_k for comps<20)
//  [128,256): rel0 * P
//  [256,384): rel1 * P
//  [384,400): rel2 * Pd (Pd = P[0..9], P[10], P[20..24])
//  [400,410): rel ; [410,420): F ; [420,424): ttv, ttv*rel0, ttv*rel1, ttv*rel2
//  [424]: gate ; [425]: 1.0 (bias) ; rest 0
__device__ float wm_value(int kk, int j, const float* __restrict__ W1,
                          const float* __restrict__ b1) {
    if (kk < 384) {
        int sec = kk >> 7;
        int rem = kk & 127;
        int w = rem >> 5, i = rem & 31;
        if (i >= 30) return 0.f;
        int q = qmap(30 * w + i);
        if (sec == 0) return W1[(11 + q) * 64 + j] + W1[(132 + q) * 64 + j];
        if (sec == 1) return W1[(253 + q) * 64 + j];
        return W1[(374 + q) * 64 + j];
    }
    if (kk < 400) {
        int i = kk - 384;
        if (i < 10) return W1[(496 + i) * 64 + j];
        if (i == 10) return W1[506 * 64 + j];
        return W1[(507 + (i - 11)) * 64 + j];
    }
    if (kk < 410) return W1[(1 + (kk - 400)) * 64 + j];
    if (kk < 420) return W1[(512 + (kk - 410)) * 64 + j];
    if (kk == 420) return W1[11 * 64 + j] + W1[132 * 64 + j];
    if (kk == 421) return W1[253 * 64 + j];
    if (kk == 422) return W1[374 * 64 + j];
    if (kk == 423) return W1[495 * 64 + j];
    if (kk == 424) return W1[0 * 64 + j];
    if (kk == 425) return b1[j];
    return 0.f;
}

// Wmf in exact B-fragment order: record (s, jb) is 64 lanes x 8 halves:
// lane (n = lane&15, quad = lane>>4) holds Wm[32s + quad*8 + idx][16jb + n].
__global__ void pack_mfma_kernel(const float* __restrict__ W1,
                                 const float* __restrict__ b1,
                                 unsigned short* __restrict__ Wmf) {
    int idx = blockIdx.x * 256 + threadIdx.x;
    if (idx >= WMF_HALVES) return;
    int half = idx & 7;
    int lane = (idx >> 3) & 63;
    int rec = idx >> 9;           // s*4 + jb
    int s = rec >> 2, jb = rec & 3;
    int kk = 32 * s + (lane >> 4) * 8 + half;
    int j = 16 * jb + (lane & 15);
    Wmf[idx] = (unsigned short)bf16rne(wm_value(kk, j, W1, b1));
}

// ---------------------------------------------------------------------------
// presig v14 (unchanged -- round-9 winner, ~98 us): two-pass scan diet +
// #pragma unroll 2 on the MFMA K-loop keeps arch-VGPR <= 128 spill-free ->
// 2 blocks/CU co-residency (unified VGPR+AGPR budget 256/wave).
// ---------------------------------------------------------------------------
__global__ __launch_bounds__(256, 2) void presig14_kernel(
    const float* __restrict__ features, const unsigned short* __restrict__ Wmf,
    float* __restrict__ pre1) {
    const int b = blockIdx.x;
    const int tid = threadIdx.x;
    const int l = tid & 63;
    const int wu = tid >> 6;

    __shared__ __align__(16) unsigned short sX[64 * XS];    // 58368 B
    __shared__ __align__(16) float sFt[65 * IND];           // 2600 B
    __shared__ float sF0[IND];                              // 40 B
    __shared__ float sBase[128];                            // 512 B

    const float* fb = features + b * (NT * IND);
    if (tid < IND) sF0[tid] = fb[tid];
    if (tid < 128) sBase[tid] = 0.f;

    for (int tile = 0; tile < 4; ++tile) {
        const int t0 = tile * 64;

        // ---- stage this tile's feature rows t0..t0+64 (coalesced) ----
        {
            const int base = t0 * IND;
            for (int idx = tid; idx < 65 * IND; idx += 256)
                sFt[idx] = fb[min(base + idx, NT * IND - 1)];
        }
        __syncthreads();   // Bs: sFt (+ sF0/sBase on tile 0) ready

        const int r = t0 + l;
        float rf = (float)r;
        float rel[IND], inc[IND];
        {
            bool last = (r >= NT - 1);
#pragma unroll
            for (int c = 0; c < IND; ++c) {
                float frc = sFt[l * IND + c];
                rel[c] = frc - sF0[c];
                inc[c] = last ? 0.f : (sFt[(l + 1) * IND + c] - frc);
            }
        }
        float inv_r = (r > 0) ? 1.f / rf : 0.f;
        const int i0 = 3 * wu - 2;
        float g0 = rel[0], g1 = rel[1], g2 = rel[2];
        float s8 = 0.f, s9 = 0.f, s10 = 0.f;   // pass-A stash for xe[1]

        // ================= pass A: components 0..15 =================
        {
            float p[16];
            if (wu == 0) {
#pragma unroll
                for (int c = 0; c < 10; ++c) p[c] = rf * inc[c];
#pragma unroll
                for (int i = 0; i < 6; ++i) p[10 + i] = rel[i];
            } else {
#pragma unroll
                for (int q = 0; q < 16; ++q) {
                    int i = i0 + q / 10, c = q % 10;
                    p[q] = rel[i] * inc[c];
                }
            }
#pragma unroll
            for (int dsh = 0; dsh < 6; ++dsh) {
                const int d = 1 << dsh;
                bool ok = (l >= d);
#pragma unroll
                for (int i = 0; i < 16; ++i) {
                    float t = __shfl_up(p[i], d, 64);
                    if (ok) p[i] += t;
                }
            }
            float v[16];
#pragma unroll
            for (int i = 0; i < 16; ++i) {
                float e = __shfl_up(p[i], 1, 64);   // exclusive = inclusive[l-1]
                float x = sBase[wu * 32 + i] + ((l >= 1) ? e : 0.f);
                if (wu == 0) x *= inv_r;            // comps 0..15 all < 20
                v[i] = x;
            }
            if (l == 63) {
#pragma unroll
                for (int i = 0; i < 16; ++i) sBase[wu * 32 + i] += p[i];
            }
            // X groups q=0 (v0..7), q=1 (v8..15)
            uint4* xr = (uint4*)&sX[l * XS];
            uint4* x0 = (uint4*)&sX[l * XS + 128];
            uint4* x1 = (uint4*)&sX[l * XS + 256];
#pragma unroll
            for (int q = 0; q < 2; ++q) {
                uint4 tr, t0v, t1v;
                tr.x = pk2(v[8*q+0], v[8*q+1]); tr.y = pk2(v[8*q+2], v[8*q+3]);
                tr.z = pk2(v[8*q+4], v[8*q+5]); tr.w = pk2(v[8*q+6], v[8*q+7]);
                t0v.x = pk2(g0*v[8*q+0], g0*v[8*q+1]); t0v.y = pk2(g0*v[8*q+2], g0*v[8*q+3]);
                t0v.z = pk2(g0*v[8*q+4], g0*v[8*q+5]); t0v.w = pk2(g0*v[8*q+6], g0*v[8*q+7]);
                t1v.x = pk2(g1*v[8*q+0], g1*v[8*q+1]); t1v.y = pk2(g1*v[8*q+2], g1*v[8*q+3]);
                t1v.z = pk2(g1*v[8*q+4], g1*v[8*q+5]); t1v.w = pk2(g1*v[8*q+6], g1*v[8*q+7]);
                xr[wu * 4 + q] = tr; x0[wu * 4 + q] = t0v; x1[wu * 4 + q] = t1v;
            }
            if (wu == 0) {   // xe[0] + stash (needs v8..v10)
                uint4* xe = (uint4*)&sX[l * XS + 384];
                uint4 u;
                u.x = pk2(g2*v[0], g2*v[1]); u.y = pk2(g2*v[2], g2*v[3]);
                u.z = pk2(g2*v[4], g2*v[5]); u.w = pk2(g2*v[6], g2*v[7]);
                xe[0] = u;
                s8 = g2 * v[8]; s9 = g2 * v[9]; s10 = g2 * v[10];
            }
        }

        // ================= pass B: components 16..29 =================
        {
            float p[14];
            if (wu == 0) {
#pragma unroll
                for (int k = 0; k < 4; ++k) p[k] = rel[6 + k];        // comps 16..19
#pragma unroll
                for (int c = 0; c < 10; ++c) p[4 + c] = rel[0] * inc[c]; // 20..29
            } else {
#pragma unroll
                for (int k = 0; k < 14; ++k) {
                    int q = 16 + k;
                    int i = i0 + q / 10, c = q % 10;
                    p[k] = rel[i] * inc[c];
                }
            }
#pragma unroll
            for (int dsh = 0; dsh < 6; ++dsh) {
                const int d = 1 << dsh;
                bool ok = (l >= d);
#pragma unroll
                for (int k = 0; k < 14; ++k) {
                    float t = __shfl_up(p[k], d, 64);
                    if (ok) p[k] += t;
                }
            }
            float v[14];
#pragma unroll
            for (int k = 0; k < 14; ++k) {
                float e = __shfl_up(p[k], 1, 64);
                float x = sBase[wu * 32 + 16 + k] + ((l >= 1) ? e : 0.f);
                if (wu == 0 && k < 4) x *= inv_r;   // comps 16..19 only
                v[k] = x;
            }
            if (l == 63) {
#pragma unroll
                for (int k = 0; k < 14; ++k) sBase[wu * 32 + 16 + k] += p[k];
            }
            // X group q=2 (v16..23 = v[0..7]) + tail (v24..29 = v[8..13])
            uint4* xr = (uint4*)&sX[l * XS];
            uint4* x0 = (uint4*)&sX[l * XS + 128];
            uint4* x1 = (uint4*)&sX[l * XS + 256];
            {
                uint4 tr, t0v, t1v;
                tr.x = pk2(v[0], v[1]); tr.y = pk2(v[2], v[3]);
                tr.z = pk2(v[4], v[5]); tr.w = pk2(v[6], v[7]);
                t0v.x = pk2(g0*v[0], g0*v[1]); t0v.y = pk2(g0*v[2], g0*v[3]);
                t0v.z = pk2(g0*v[4], g0*v[5]); t0v.w = pk2(g0*v[6], g0*v[7]);
                t1v.x = pk2(g1*v[0], g1*v[1]); t1v.y = pk2(g1*v[2], g1*v[3]);
                t1v.z = pk2(g1*v[4], g1*v[5]); t1v.w = pk2(g1*v[6], g1*v[7]);
                xr[wu * 4 + 2] = tr; x0[wu * 4 + 2] = t0v; x1[wu * 4 + 2] = t1v;
            }
            {   // tail: v[24..29] + 2 zero halves
                uint4 tr, t0v, t1v;
                tr.x = pk2(v[8], v[9]);   tr.y = pk2(v[10], v[11]);
                tr.z = pk2(v[12], v[13]); tr.w = 0u;
                t0v.x = pk2(g0*v[8], g0*v[9]);   t0v.y = pk2(g0*v[10], g0*v[11]);
                t0v.z = pk2(g0*v[12], g0*v[13]); t0v.w = 0u;
                t1v.x = pk2(g1*v[8], g1*v[9]);   t1v.y = pk2(g1*v[10], g1*v[11]);
                t1v.z = pk2(g1*v[12], g1*v[13]); t1v.w = 0u;
                xr[wu * 4 + 3] = tr; x0[wu * 4 + 3] = t0v; x1[wu * 4 + 3] = t1v;
            }
            if (wu == 0) {   // extras xe[1..7]; comps 20..24 are v[4..8] here
                float ttv = 0.5f * (rf - 1.f) * inv_r;
                float gate = (r > 0) ? 1.f : 0.f;
                float fr0 = rel[0] + sF0[0], fr1 = rel[1] + sF0[1];
                float fr2 = rel[2] + sF0[2], fr3 = rel[3] + sF0[3];
                float fr4 = rel[4] + sF0[4], fr5 = rel[5] + sF0[5];
                float fr6 = rel[6] + sF0[6], fr7 = rel[7] + sF0[7];
                float fr8 = rel[8] + sF0[8], fr9 = rel[9] + sF0[9];
                uint4* xe = (uint4*)&sX[l * XS + 384];
                uint4 u;
                u.x = pk2(s8, s9);             u.y = pk2(s10, g2 * v[4]);
                u.z = pk2(g2*v[5], g2*v[6]);   u.w = pk2(g2*v[7], g2*v[8]);
                xe[1] = u;
                u.x = pk2(rel[0], rel[1]); u.y = pk2(rel[2], rel[3]);
                u.z = pk2(rel[4], rel[5]); u.w = pk2(rel[6], rel[7]);
                xe[2] = u;
                u.x = pk2(rel[8], rel[9]); u.y = pk2(fr0, fr1);
                u.z = pk2(fr2, fr3);       u.w = pk2(fr4, fr5);
                xe[3] = u;
                u.x = pk2(fr6, fr7); u.y = pk2(fr8, fr9);
                u.z = pk2(ttv, ttv * rel[0]); u.w = pk2(ttv * rel[1], ttv * rel[2]);
                xe[4] = u;
                u.x = pk2(gate, 1.0f); u.y = 0u; u.z = 0u; u.w = 0u;
                xe[5] = u;
                u.x = 0u; u.y = 0u; u.z = 0u; u.w = 0u;
                xe[6] = u; xe[7] = u;
            }
        }
        __syncthreads();   // Bx: X complete (cross-wave reads next)

        // ---- MFMA j-phase: unroll 2 bounds in-flight B-frags (~8 loads) ----
        {
            const int m = l & 15, quad = l >> 4;
            const unsigned short* arow = &sX[(16 * wu + m) * XS + 8 * quad];
            const bf16x8* bp = (const bf16x8*)Wmf;
            f32x4 ac0 = {0.f, 0.f, 0.f, 0.f}, ac1 = ac0, ac2 = ac0, ac3 = ac0;
#pragma unroll 2
            for (int s = 0; s < KSTEPS; ++s) {
                bf16x8 af = *(const bf16x8*)(arow + 32 * s);
                bf16x8 bf0 = bp[(s * 4 + 0) * 64 + l];
                bf16x8 bf1 = bp[(s * 4 + 1) * 64 + l];
                bf16x8 bf2 = bp[(s * 4 + 2) * 64 + l];
                bf16x8 bf3 = bp[(s * 4 + 3) * 64 + l];
                ac0 = __builtin_amdgcn_mfma_f32_16x16x32_bf16(af, bf0, ac0, 0, 0, 0);
                ac1 = __builtin_amdgcn_mfma_f32_16x16x32_bf16(af, bf1, ac1, 0, 0, 0);
                ac2 = __builtin_amdgcn_mfma_f32_16x16x32_bf16(af, bf2, ac2, 0, 0, 0);
                ac3 = __builtin_amdgcn_mfma_f32_16x16x32_bf16(af, bf3, ac3, 0, 0, 0);
            }
            float* op = pre1 + b * (NT * HID) + (t0 + 16 * wu) * HID + m;
            const int rowb = quad * 4;
#pragma unroll
            for (int reg = 0; reg < 4; ++reg) {
                op[(rowb + reg) * HID + 0]  = ac0[reg];
                op[(rowb + reg) * HID + 16] = ac1[reg];
                op[(rowb + reg) * HID + 32] = ac2[reg];
                op[(rowb + reg) * HID + 48] = ac3[reg];
            }
        }
        __syncthreads();   // Be: all X reads done before next tile rewrites
    }
}

// ---------------------------------------------------------------------------
// scan v10 (scan10_kernel): UNBUNDLE of round-14.  scan9b (104 us) bundled
// two chain edits and regressed vs scan6 (98.5): the independent MFMA pair
// DOUBLED the MFMA->VALU hazard reads (8 accumulator tuples read by VALU
// adds instead of 4); MFMA->MFMA same-accumulator forwarding is cheaper.
// But scan9b PASSED (absmax 1.0), hardware-verifying the 16-lane-coverage
// reduce: lane (m,q) reg0 = full 64-K dot for cols {m,16+m,32+m,48+m}, so
// sum of lanes 0..15 = full GEMV; 4 row_shr stages land the row sum in
// lane 15.  scan10 = scan6's CHAINED MFMAs (proven fast) + scan9b's
// VERIFIED 4-stage reduce + readlane(15) + raw W3 (no 0.25 prescale).
// Discriminator: ~95-97 us = reduce win; ~98.5 = hazard floor (declare
// structural ceiling: 256 serial steps x ~925 cy of a nonlinear recurrence
// -- not associative-scannable -- x all chains already concurrent).
// ---------------------------------------------------------------------------
template <int CTRL, int RMASK>
__device__ __forceinline__ float dpp_add(float x) {
    int v = __builtin_amdgcn_update_dpp(0, __float_as_int(x), CTRL, RMASK, 0xf, false);
    return x + __int_as_float(v);
}

__device__ __forceinline__ float rl(float x, int lane) {
    return __uint_as_float(__builtin_amdgcn_readlane(__float_as_uint(x), lane));
}

__global__ __launch_bounds__(64, 1) void scan10_kernel(
    const float* __restrict__ pre1, const float* __restrict__ W1,
    const float* __restrict__ W2, const float* __restrict__ b2,
    const float* __restrict__ W3, const float* __restrict__ b3,
    float* __restrict__ out) {
    const int b = blockIdx.x;
    const int l = threadIdx.x;
    const int m = l & 15, q = l >> 4;

    // ---- W2 B-fragments (8 x bf16x8 = 32 VGPRs), built once ----
#define BUILD_B(dst, ks, nb) { \
        const int k0 = 32 * (ks) + 8 * q; \
        const int n = 16 * (nb) + m; \
        float x0 = W2[(k0 + 0) * 64 + n], x1 = W2[(k0 + 1) * 64 + n]; \
        float x2 = W2[(k0 + 2) * 64 + n], x3 = W2[(k0 + 3) * 64 + n]; \
        float x4 = W2[(k0 + 4) * 64 + n], x5 = W2[(k0 + 5) * 64 + n]; \
        float x6 = W2[(k0 + 6) * 64 + n], x7 = W2[(k0 + 7) * 64 + n]; \
        unsigned u0, u1, u2, u3; \
        asm("v_cvt_pk_bf16_f32 %0, %1, %2" : "=v"(u0) : "v"(x0), "v"(x1)); \
        asm("v_cvt_pk_bf16_f32 %0, %1, %2" : "=v"(u1) : "v"(x2), "v"(x3)); \
        asm("v_cvt_pk_bf16_f32 %0, %1, %2" : "=v"(u2) : "v"(x4), "v"(x5)); \
        asm("v_cvt_pk_bf16_f32 %0, %1, %2" : "=v"(u3) : "v"(x6), "v"(x7)); \
        union { unsigned uu[4]; bf16x8 v; } cv; \
        cv.uu[0] = u0; cv.uu[1] = u1; cv.uu[2] = u2; cv.uu[3] = u3; \
        dst = cv.v; }

    bf16x8 Bf0, Bf1, Bf2, Bf3, Bf4, Bf5, Bf6, Bf7;
    BUILD_B(Bf0, 0, 0) BUILD_B(Bf1, 0, 1) BUILD_B(Bf2, 0, 2) BUILD_B(Bf3, 0, 3)
    BUILD_B(Bf4, 1, 0) BUILD_B(Bf5, 1, 1) BUILD_B(Bf6, 1, 2) BUILD_B(Bf7, 1, 3)
#undef BUILD_B

    // ---- per-lane invariants ----
    float w1a[8], w1b[8];
#pragma unroll
    for (int i = 0; i < 8; ++i) {
        w1a[i] = W1[522 * 64 + 8 * q + i];
        w1b[i] = W1[522 * 64 + 32 + 8 * q + i];
    }
    float b2s0 = b2[m],      b2s1 = b2[16 + m],
          b2s2 = b2[32 + m], b2s3 = b2[48 + m];
    float w3s0 = W3[m],      w3s1 = W3[16 + m],
          w3s2 = W3[32 + m], w3s3 = W3[48 + m];   // raw (16-lane reduce)
    float b3v = b3[0];

    const float* pb_ = pre1 + b * (NT * HID);
    const int o1 = 8 * q, o2 = 8 * q + 4, o3 = 32 + 8 * q, o4 = 36 + 8 * q;
    float delta = 0.f;
    float outbuf = 0.f;

#define STEP10(pa, pb, pc, pd, mm) { \
        float hA0 = fmaxf(fmaf(delta, w1a[0], (pa).x), 0.f); \
        float hA1 = fmaxf(fmaf(delta, w1a[1], (pa).y), 0.f); \
        float hA2 = fmaxf(fmaf(delta, w1a[2], (pa).z), 0.f); \
        float hA3 = fmaxf(fmaf(delta, w1a[3], (pa).w), 0.f); \
        float hA4 = fmaxf(fmaf(delta, w1a[4], (pb).x), 0.f); \
        float hA5 = fmaxf(fmaf(delta, w1a[5], (pb).y), 0.f); \
        float hA6 = fmaxf(fmaf(delta, w1a[6], (pb).z), 0.f); \
        float hA7 = fmaxf(fmaf(delta, w1a[7], (pb).w), 0.f); \
        float hB0 = fmaxf(fmaf(delta, w1b[0], (pc).x), 0.f); \
        float hB1 = fmaxf(fmaf(delta, w1b[1], (pc).y), 0.f); \
        float hB2 = fmaxf(fmaf(delta, w1b[2], (pc).z), 0.f); \
        float hB3 = fmaxf(fmaf(delta, w1b[3], (pc).w), 0.f); \
        float hB4 = fmaxf(fmaf(delta, w1b[4], (pd).x), 0.f); \
        float hB5 = fmaxf(fmaf(delta, w1b[5], (pd).y), 0.f); \
        float hB6 = fmaxf(fmaf(delta, w1b[6], (pd).z), 0.f); \
        float hB7 = fmaxf(fmaf(delta, w1b[7], (pd).w), 0.f); \
        unsigned uA0, uA1, uA2, uA3, uB0, uB1, uB2, uB3; \
        asm("v_cvt_pk_bf16_f32 %0, %1, %2" : "=v"(uA0) : "v"(hA0), "v"(hA1)); \
        asm("v_cvt_pk_bf16_f32 %0, %1, %2" : "=v"(uA1) : "v"(hA2), "v"(hA3)); \
        asm("v_cvt_pk_bf16_f32 %0, %1, %2" : "=v"(uA2) : "v"(hA4), "v"(hA5)); \
        asm("v_cvt_pk_bf16_f32 %0, %1, %2" : "=v"(uA3) : "v"(hA6), "v"(hA7)); \
        asm("v_cvt_pk_bf16_f32 %0, %1, %2" : "=v"(uB0) : "v"(hB0), "v"(hB1)); \
        asm("v_cvt_pk_bf16_f32 %0, %1, %2" : "=v"(uB1) : "v"(hB2), "v"(hB3)); \
        asm("v_cvt_pk_bf16_f32 %0, %1, %2" : "=v"(uB2) : "v"(hB4), "v"(hB5)); \
        asm("v_cvt_pk_bf16_f32 %0, %1, %2" : "=v"(uB3) : "v"(hB6), "v"(hB7)); \
        union { unsigned uu[4]; bf16x8 v; } cA, cB; \
        cA.uu[0] = uA0; cA.uu[1] = uA1; cA.uu[2] = uA2; cA.uu[3] = uA3; \
        cB.uu[0] = uB0; cB.uu[1] = uB1; cB.uu[2] = uB2; cB.uu[3] = uB3; \
        f32x4 z = {0.f, 0.f, 0.f, 0.f}; \
        f32x4 c0 = __builtin_amdgcn_mfma_f32_16x16x32_bf16(cA.v, Bf0, z, 0, 0, 0); \
        f32x4 c1 = __builtin_amdgcn_mfma_f32_16x16x32_bf16(cA.v, Bf1, z, 0, 0, 0); \
        f32x4 c2 = __builtin_amdgcn_mfma_f32_16x16x32_bf16(cA.v, Bf2, z, 0, 0, 0); \
        f32x4 c3 = __builtin_amdgcn_mfma_f32_16x16x32_bf16(cA.v, Bf3, z, 0, 0, 0); \
        c0 = __builtin_amdgcn_mfma_f32_16x16x32_bf16(cB.v, Bf4, c0, 0, 0, 0); \
        c1 = __builtin_amdgcn_mfma_f32_16x16x32_bf16(cB.v, Bf5, c1, 0, 0, 0); \
        c2 = __builtin_amdgcn_mfma_f32_16x16x32_bf16(cB.v, Bf6, c2, 0, 0, 0); \
        c3 = __builtin_amdgcn_mfma_f32_16x16x32_bf16(cB.v, Bf7, c3, 0, 0, 0); \
        float e0 = fmaxf(c0[0] + b2s0, 0.f) * w3s0; \
        float e1 = fmaxf(c1[0] + b2s1, 0.f) * w3s1; \
        float e2 = fmaxf(c2[0] + b2s2, 0.f) * w3s2; \
        float e3 = fmaxf(c3[0] + b2s3, 0.f) * w3s3; \
        float qv = (e0 + e1) + (e2 + e3); \
        qv = dpp_add<0x111, 0xf>(qv); \
        qv = dpp_add<0x112, 0xf>(qv); \
        qv = dpp_add<0x114, 0xf>(qv); \
        qv = dpp_add<0x118, 0xf>(qv); \
        delta = rl(qv, 15) + b3v; \
        if (l == ((mm) & 63)) outbuf = delta; \
        if (((mm) & 63) == 63) out[b * NT + ((mm) & ~63) + l] = outbuf; }

    // ---- ping-pong 4-step prefetch ring (no register rotation) ----
    float4 s0a, s0b, s0c, s0d, s1a, s1b, s1c, s1d,
           s2a, s2b, s2c, s2d, s3a, s3b, s3c, s3d;
    float4 t0a, t0b, t0c, t0d, t1a, t1b, t1c, t1d,
           t2a, t2b, t2c, t2d, t3a, t3b, t3c, t3d;
#define LD(dsta, dstb, dstc, dstd, tt) { \
        const float* base = &pb_[(tt) * 64]; \
        dsta = *(const float4*)&base[o1]; dstb = *(const float4*)&base[o2]; \
        dstc = *(const float4*)&base[o3]; dstd = *(const float4*)&base[o4]; }

    LD(s0a, s0b, s0c, s0d, 0) LD(s1a, s1b, s1c, s1d, 1)
    LD(s2a, s2b, s2c, s2d, 2) LD(s3a, s3b, s3c, s3d, 3)
    LD(t0a, t0b, t0c, t0d, 4) LD(t1a, t1b, t1c, t1d, 5)
    LD(t2a, t2b, t2c, t2d, 6) LD(t3a, t3b, t3c, t3d, 7)

    for (int g = 0; g < NT; g += 8) {
        STEP10(s0a, s0b, s0c, s0d, g + 0)
        STEP10(s1a, s1b, s1c, s1d, g + 1)
        STEP10(s2a, s2b, s2c, s2d, g + 2)
        STEP10(s3a, s3b, s3c, s3d, g + 3)
        LD(s0a, s0b, s0c, s0d, min(g + 8,  NT - 1))
        LD(s1a, s1b, s1c, s1d, min(g + 9,  NT - 1))
        LD(s2a, s2b, s2c, s2d, min(g + 10, NT - 1))
        LD(s3a, s3b, s3c, s3d, min(g + 11, NT - 1))
        STEP10(t0a, t0b, t0c, t0d, g + 4)
        STEP10(t1a, t1b, t1c, t1d, g + 5)
        STEP10(t2a, t2b, t2c, t2d, g + 6)
        STEP10(t3a, t3b, t3c, t3d, g + 7)
        LD(t0a, t0b, t0c, t0d, min(g + 12, NT - 1))
        LD(t1a, t1b, t1c, t1d, min(g + 13, NT - 1))
        LD(t2a, t2b, t2c, t2d, min(g + 14, NT - 1))
        LD(t3a, t3b, t3c, t3d, min(g + 15, NT - 1))
    }
#undef LD
#undef STEP10
}

// ---------------------------------------------------------------------------
// Fallback (round-1 fused kernel) if workspace is too small.
// ---------------------------------------------------------------------------
__global__ __launch_bounds__(256) void logsig_hedge_fallback(
    const float* __restrict__ features, const float* __restrict__ W1,
    const float* __restrict__ b1, const float* __restrict__ W2,
    const float* __restrict__ b2, const float* __restrict__ W3,
    const float* __restrict__ b3, float* __restrict__ out) {
    const int b = blockIdx.x;
    const int tid = threadIdx.x;
    const int j = tid & 63;
    const int s = tid >> 6;

    __shared__ __align__(16) float sF[NT * IND];
    __shared__ __align__(16) float sSig[128];
    __shared__ float sA[IND], sB[IND], sC[IND * IND];
    __shared__ float sRel[IND];
    __shared__ __align__(16) float sPart[4 * 64];
    __shared__ __align__(16) float sH1[64];

    for (int idx = tid; idx < NT * IND; idx += 256)
        sF[idx] = features[b * (NT * IND) + idx];
    if (tid < 100) sC[tid] = 0.f;
    else if (tid < 110) sA[tid - 100] = 0.f;
    else if (tid < 120) sB[tid - 110] = 0.f;
    else if (tid >= 121 && tid < 128) sSig[tid] = 0.f;

    float vs[32], vb[32], vc[32];
#pragma unroll
    for (int mm = 0; mm < 32; ++mm) {
        int mp = 32 * s + mm;
        if (mp < 121) {
            vs[mm] = W1[(11 + mp) * 64 + j] + W1[(132 + mp) * 64 + j];
            vb[mm] = W1[(253 + mp) * 64 + j];
            vc[mm] = W1[(374 + mp) * 64 + j];
        } else { vs[mm] = 0.f; vb[mm] = 0.f; vc[mm] = 0.f; }
    }
    float ex[17];
#pragma unroll
    for (int q = 0; q < 17; ++q) ex[q] = 0.f;
    if (s == 1) {
#pragma unroll
        for (int q = 0; q < 11; ++q) ex[q] = W1[q * 64 + j];
    } else if (s == 2) {
#pragma unroll
        for (int q = 0; q < 10; ++q) ex[q] = W1[(512 + q) * 64 + j];
        ex[10] = b1[j];
    } else if (s == 3) {
#pragma unroll
        for (int q = 0; q < 17; ++q) ex[q] = W1[(495 + q) * 64 + j];
    }
    float w2p[16];
#pragma unroll
    for (int ii = 0; ii < 16; ++ii) w2p[ii] = W2[(16 * s + ii) * 64 + j];

    float w1l = 0.f, b2j = 0.f, w3j = 0.f, b3v = 0.f;
    if (s == 0) { w1l = W1[522 * 64 + j]; b2j = b2[j]; w3j = W3[j]; b3v = b3[0]; }
    float delta = 0.f;

    __syncthreads();

    for (int m = 0; m < NT; ++m) {
        if (m > 0) {
            if (tid < 100) {
                int i = tid / 10, c = tid % 10;
                float rp = sF[(m - 1) * 10 + i] - sF[i];
                float ic = sF[m * 10 + c] - sF[(m - 1) * 10 + c];
                sC[tid] += rp * ic;
            } else if (tid < 110) {
                int i = tid - 100;
                sA[i] += (float)(m - 1) * (sF[m * 10 + i] - sF[(m - 1) * 10 + i]);
            } else if (tid < 120) {
                int i = tid - 110;
                sB[i] += sF[(m - 1) * 10 + i] - sF[i];
            }
            __syncthreads();
            float inv_k = 1.0f / (float)m;
            if (tid == 0) sSig[0] = 0.5f * (float)(m - 1) * inv_k;
            else if (tid < 11) sSig[tid] = inv_k * sA[tid - 1];
            else if (tid < 121) {
                int i = tid / 11 - 1, c = tid % 11;
                sSig[tid] = (c == 0) ? inv_k * sB[i] : sC[i * 10 + (c - 1)];
            } else if (tid < 131) {
                int f = tid - 121;
                sRel[f] = sF[m * 10 + f] - sF[f];
            }
            __syncthreads();
        }
        float part = 0.f;
        if (m > 0) {
            float pa = 0.f, pb = 0.f, pc = 0.f;
#pragma unroll
            for (int q = 0; q < 8; ++q) {
                float4 sv = *(const float4*)&sSig[32 * s + 4 * q];
                pa = fmaf(sv.x, vs[4 * q + 0], pa);
                pb = fmaf(sv.x, vb[4 * q + 0], pb);
                pc = fmaf(sv.x, vc[4 * q + 0], pc);
                pa = fmaf(sv.y, vs[4 * q + 1], pa);
                pb = fmaf(sv.y, vb[4 * q + 1], pb);
                pc = fmaf(sv.y, vc[4 * q + 1], pc);
                pa = fmaf(sv.z, vs[4 * q + 2], pa);
                pb = fmaf(sv.z, vb[4 * q + 2], pb);
                pc = fmaf(sv.z, vc[4 * q + 2], pc);
                pa = fmaf(sv.w, vs[4 * q + 3], pa);
                pb = fmaf(sv.w, vb[4 * q + 3], pb);
                pc = fmaf(sv.w, vc[4 * q + 3], pc);
            }
            part = pa + sRel[0] * pb + sRel[1] * pc;
            if (s == 3) {
                float pd = 0.f;
#pragma unroll
                for (int q = 0; q < 17; ++q) pd = fmaf(sSig[q], ex[q], pd);
                part = fmaf(sRel[2], pd, part);
            }
            if (s == 1) {
                part += ex[0];
#pragma unroll
                for (int i = 0; i < 10; ++i) part = fmaf(sRel[i], ex[1 + i], part);
            }
        }
        if (s == 2) {
            float pf = ex[10];
#pragma unroll
            for (int f = 0; f < 10; ++f) pf = fmaf(sF[m * 10 + f], ex[f], pf);
            part += pf;
        }
        sPart[s * 64 + j] = part;
        __syncthreads();
        if (s == 0) {
            float x = sPart[j] + sPart[64 + j] + sPart[128 + j] + sPart[192 + j];
            sH1[j] = fmaxf(fmaf(delta, w1l, x), 0.f);
        }
        __syncthreads();
        {
            float hp = 0.f;
#pragma unroll
            for (int q = 0; q < 4; ++q) {
                float4 hv = *(const float4*)&sH1[16 * s + 4 * q];
                hp = fmaf(hv.x, w2p[4 * q + 0], hp);
                hp = fmaf(hv.y, w2p[4 * q + 1], hp);
                hp = fmaf(hv.z, w2p[4 * q + 2], hp);
                hp = fmaf(hv.w, w2p[4 * q + 3], hp);
            }
            sPart[s * 64 + j] = hp;
        }
        __syncthreads();
        if (s == 0) {
            float x2 = sPart[j] + sPart[64 + j] + sPart[128 + j] + sPart[192 + j] + b2j;
            float h2 = fmaxf(x2, 0.f);
            float dv = h2 * w3j;
#pragma unroll
            for (int off = 32; off > 0; off >>= 1) dv += __shfl_xor(dv, off, 64);
            delta = dv + b3v;
            if (j == 0) out[b * NT + m] = delta;
        }
        __syncthreads();
    }
}

extern "C" void kernel_launch(void* const* d_in, const int* in_sizes, int n_in,
                              void* d_out, int out_size, void* d_ws, size_t ws_size,
                              hipStream_t stream) {
    const float* features = (const float*)d_in[0];
    const float* W1 = (const float*)d_in[1];
    const float* b1 = (const float*)d_in[2];
    const float* W2 = (const float*)d_in[3];
    const float* b2 = (const float*)d_in[4];
    const float* W3 = (const float*)d_in[5];
    const float* b3 = (const float*)d_in[6];
    float* out = (float*)d_out;

    const size_t wmf_bytes = (size_t)WMF_HALVES * 2;                 // 57344
    const size_t w_pad     = ((wmf_bytes + 255) / 256) * 256;
    const size_t pre_bytes = (size_t)NB * NT * HID * sizeof(float);  // 64 MiB
    if (ws_size >= w_pad + pre_bytes) {
        unsigned short* Wmf = (unsigned short*)d_ws;
        float* pre1 = (float*)((char*)d_ws + w_pad);
        pack_mfma_kernel<<<(WMF_HALVES + 255) / 256, 256, 0, stream>>>(W1, b1, Wmf);
        presig14_kernel<<<NB, 256, 0, stream>>>(features, Wmf, pre1);
        scan10_kernel<<<NB, 64, 0, stream>>>(pre1, W1, W2, b2, W3, b3, out);
    } else {
        logsig_hedge_fallback<<<NB, 256, 0, stream>>>(features, W1, b1, W2, b2, W3, b3, out);
    }
}